// Round 3
// baseline (1521.778 us; speedup 1.0000x reference)
//
#include <hip/hip_runtime.h>

#define BEVW 432
#define BEVH 496
#define NCELL (BEVW*BEVH)      // 214272
#define NVOX  40000
#define EPSB  1e-5f

typedef float f32x16 __attribute__((ext_vector_type(16)));

// ---------------- workspace layout (bytes) ----------------
// 0        : int nact                (zeroed)
// 256      : int cnt[NCELL]          (zeroed)          857088
// 857600   : int list[NCELL*16]                        13713408
// 14571008 : float voxelwise[NVOX*64]                  10240000
// 24811008 : int act[NVOX]                             160000
// 24971008 : float x17g[NVOX*128]                      20480000
// 45451008 : float fold[1168]
// 45455680 : float w4t[4096]
// total ~45.5 MB

__device__ __forceinline__ float mishf(float y) {
    float e = __expf(fminf(y, 40.f));
    float n = e * (e + 2.f);
    return y * n * __builtin_amdgcn_rcpf(n + 2.f);
}

// 32-lane max reduce (group = one voxel)
#define WMAX32(a) { a = fmaxf(a, __shfl_xor(a, 16)); a = fmaxf(a, __shfl_xor(a, 8)); \
                    a = fmaxf(a, __shfl_xor(a, 4));  a = fmaxf(a, __shfl_xor(a, 2)); \
                    a = fmaxf(a, __shfl_xor(a, 1)); }

// fold layout (floats):
// vfe1: s@0  t@8   | vfe2: s@16 t@48 | vfe3: s@80 t@144 | vfe4: s@208 t@272
// bfe3: s@336 t@464 | bfe1: s@592 t@848 | bfe2: s@1104 t@1136
__global__ __launch_bounds__(256) void setup_kernel(
    const float* __restrict__ vbn1, const float* __restrict__ vbn2,
    const float* __restrict__ vbn3, const float* __restrict__ vbn4,
    const float* __restrict__ bbn1, const float* __restrict__ bbn2,
    const float* __restrict__ bbn3, const float* __restrict__ W4,
    float* __restrict__ fold, float* __restrict__ w4t)
{
    int tid = threadIdx.x;
    if (tid < 8)  { float s = vbn1[tid]/sqrtf(vbn1[24+tid]+EPSB);  fold[tid]      = s; fold[8+tid]   = vbn1[8+tid]  - vbn1[16+tid]*s; }
    if (tid < 32) { float s = vbn2[tid]/sqrtf(vbn2[96+tid]+EPSB);  fold[16+tid]   = s; fold[48+tid]  = vbn2[32+tid] - vbn2[64+tid]*s; }
    if (tid < 64) { float s = vbn3[tid]/sqrtf(vbn3[192+tid]+EPSB); fold[80+tid]   = s; fold[144+tid] = vbn3[64+tid] - vbn3[128+tid]*s; }
    if (tid < 64) { float s = vbn4[tid]/sqrtf(vbn4[192+tid]+EPSB); fold[208+tid]  = s; fold[272+tid] = vbn4[64+tid] - vbn4[128+tid]*s; }
    if (tid < 128){ float s = bbn3[tid]/sqrtf(bbn3[384+tid]+EPSB); fold[336+tid]  = s; fold[464+tid] = bbn3[128+tid]- bbn3[256+tid]*s; }
    { // bfe1_bn [16][4][16]
        int g = tid >> 4, q = tid & 15;
        const float* b = bbn1 + g*64;
        float s = b[q]/sqrtf(b[48+q]+EPSB);
        fold[592+tid] = s; fold[848+tid] = b[16+q] - b[32+q]*s;
    }
    if (tid < 32) { // bfe2_bn [16][4][2]
        int g = tid >> 1, c = tid & 1;
        const float* b = bbn2 + g*8;
        float s = b[c]/sqrtf(b[6+c]+EPSB);
        fold[1104+tid] = s; fold[1136+tid] = b[2+c] - b[4+c]*s;
    }
    for (int i = tid; i < 4096; i += 256) { int o = i >> 6, c = i & 63; w4t[c*64+o] = W4[i]; }
}

// ---------------- VFE: 8 voxels / 256-thread block, lane=point ----------------
// ALL per-thread state in named ext_vector registers: no allocas -> no scratch.
// (Rounds 1-2: float arrays were demoted to scratch pre-RA -> 34 GB spill traffic.)
__global__ __launch_bounds__(256, 2) void vfe_kernel(
    const float* __restrict__ feat, const int* __restrict__ coors,
    const int* __restrict__ nvx,
    const float* __restrict__ W1, const float* __restrict__ W2,
    const float* __restrict__ W3, const float* __restrict__ W4T,
    const float* __restrict__ fold,
    float* __restrict__ voxelwise, int* __restrict__ cnt,
    int* __restrict__ list, int* __restrict__ nact, int* __restrict__ act)
{
    int tid = threadIdx.x;
    int v = blockIdx.x * 8 + (tid >> 5);
    int t = tid & 31;

    const float* fp = feat + (v*32 + t)*8;
    float4 fa = *(const float4*)fp;
    float4 fb = *(const float4*)(fp+4);

    int numv = nvx[v];
    float maskf = (t < numv) ? 1.f : 0.f;

    // fe1 (8->8) + maxpool -> x1v[16]
    f32x16 x1v;
#pragma unroll
    for (int o = 0; o < 8; o++) {
        float y0 = fa.x*W1[o*8+0] + fa.y*W1[o*8+1];
        float y1 = fa.z*W1[o*8+2] + fa.w*W1[o*8+3];
        float y2 = fb.x*W1[o*8+4] + fb.y*W1[o*8+5];
        float y3 = fb.z*W1[o*8+6] + fb.w*W1[o*8+7];
        float y = ((y0+y1) + (y2+y3)) * fold[0+o] + fold[8+o];
        x1v[o] = mishf(y);
    }
#pragma unroll
    for (int o = 0; o < 8; o++) {
        float a = x1v[o];
        WMAX32(a);
        x1v[8+o] = a;
    }

    // fe2 (16->32) + maxpool -> x2 chunks a/b (pointwise) c/d (agg), masked
    f32x16 x2a, x2b, x2c, x2d;
#pragma unroll
    for (int o = 0; o < 16; o++) {
        float y0 = 0.f, y1 = 0.f;
#pragma unroll
        for (int c = 0; c < 8; c++) {
            y0 += x1v[c]   * W2[o*16+c];
            y1 += x1v[8+c] * W2[o*16+8+c];
        }
        x2a[o] = mishf((y0 + y1) * fold[16+o] + fold[48+o]);
    }
#pragma unroll
    for (int o = 0; o < 16; o++) {
        float y0 = 0.f, y1 = 0.f;
#pragma unroll
        for (int c = 0; c < 8; c++) {
            y0 += x1v[c]   * W2[(16+o)*16+c];
            y1 += x1v[8+c] * W2[(16+o)*16+8+c];
        }
        x2b[o] = mishf((y0 + y1) * fold[32+o] + fold[64+o]);
    }
#pragma unroll
    for (int o = 0; o < 16; o++) {
        float a = x2a[o];
        WMAX32(a);
        x2c[o] = a * maskf;
        x2a[o] *= maskf;
    }
#pragma unroll
    for (int o = 0; o < 16; o++) {
        float a = x2b[o];
        WMAX32(a);
        x2d[o] = a * maskf;
        x2b[o] *= maskf;
    }

    // fe3 (64->64); fe4 accumulated incrementally via W4T (x3 never stored)
    f32x16 ac0, ac1, ac2, ac3;
#pragma unroll
    for (int q = 0; q < 16; q++) { ac0[q] = 0.f; ac1[q] = 0.f; ac2[q] = 0.f; ac3[q] = 0.f; }
#pragma unroll 2
    for (int o = 0; o < 64; o++) {
        const float* w3r = W3 + o*64;
        float y0 = 0.f, y1 = 0.f, y2 = 0.f, y3 = 0.f;
#pragma unroll
        for (int c = 0; c < 16; c++) {
            y0 += x2a[c] * w3r[c];
            y1 += x2b[c] * w3r[16+c];
            y2 += x2c[c] * w3r[32+c];
            y3 += x2d[c] * w3r[48+c];
        }
        float y = ((y0+y1) + (y2+y3)) * fold[80+o] + fold[144+o];
        float x3 = mishf(y);
        const float* w4r = W4T + o*64;
#pragma unroll
        for (int q = 0; q < 16; q++) {
            ac0[q] += x3 * w4r[q];
            ac1[q] += x3 * w4r[16+q];
            ac2[q] += x3 * w4r[32+q];
            ac3[q] += x3 * w4r[48+q];
        }
    }

    // bn4 + mish, residual, max over 32 points (invalid lanes contribute exact 0)
#pragma unroll
    for (int q = 0; q < 16; q++) {
        float y = ac0[q] * fold[208+q] + fold[272+q];
        y = mishf(y) * maskf + x2a[q];
        WMAX32(y);
        x2a[q] = y;
    }
#pragma unroll
    for (int q = 0; q < 16; q++) {
        float y = ac1[q] * fold[224+q] + fold[288+q];
        y = mishf(y) * maskf + x2b[q];
        WMAX32(y);
        x2b[q] = y;
    }
#pragma unroll
    for (int q = 0; q < 16; q++) {
        float y = ac2[q] * fold[240+q] + fold[304+q];
        y = mishf(y) * maskf + x2c[q];
        WMAX32(y);
        x2c[q] = y;
    }
#pragma unroll
    for (int q = 0; q < 16; q++) {
        float y = ac3[q] * fold[256+q] + fold[320+q];
        y = mishf(y) * maskf + x2d[q];
        WMAX32(y);
        x2d[q] = y;
    }

    if (t == 0) {
        f32x16* dst = (f32x16*)(voxelwise + v*64);
        dst[0] = x2a; dst[1] = x2b; dst[2] = x2c; dst[3] = x2d;
        int cell = coors[v*2] * BEVW + coors[v*2+1];
        int pos = atomicAdd(&cnt[cell], 1);
        if (pos < 16) list[cell*16 + pos] = v;
        if (pos == 0) { int k = atomicAdd(nact, 1); act[k] = cell; }
    }
}

// ---------------- BFE front (bfe1+bfe2): 1 wave = 1 active cell ----------------
__global__ __launch_bounds__(256) void bfe_front(
    const int* __restrict__ nact, const int* __restrict__ act,
    const int* __restrict__ cnt, const int* __restrict__ list,
    const float* __restrict__ voxelwise,
    const float* __restrict__ W1g, const float* __restrict__ W2g,
    const float* __restrict__ fold, float* __restrict__ x17g)
{
    __shared__ float W1L[16*257];   // [g][q*16+p], stride 257 -> conflict-free
    __shared__ float W2L[16*33];    // [g][c*16+p], stride 33
    for (int i = threadIdx.x; i < 4096; i += 256) W1L[(i>>8)*257 + (i&255)] = W1g[i];
    for (int i = threadIdx.x; i < 512;  i += 256) W2L[(i>>5)*33  + (i&31)]  = W2g[i];
    __syncthreads();

    int n_act = *nact;
    int aidx = blockIdx.x * 4 + (threadIdx.x >> 6);
    if (aidx >= n_act) return;                   // wave-uniform

    int lane = threadIdx.x & 63;
    int g = lane >> 2, ii = lane & 3;
    int cell = act[aidx];
    int numv = min(cnt[cell], 16);

    // sort kept voxel indices ascending (slot order = original-index order)
    int myidx = (lane < numv) ? list[cell*16 + lane] : (0x40000000 + lane);
    int rank = 0;
    for (int j = 0; j < numv; j++) { int vj = __shfl(myidx, j); rank += (vj < myidx) ? 1 : 0; }
    if (lane >= numv) rank = lane;
    int sorted = __builtin_amdgcn_ds_permute(rank << 2, myidx);

    // bfe1: y[q] = sum_p val[p]*W1[g][q][p]  (val[p]=0 for p>=numv)
    f32x16 y;
#pragma unroll
    for (int q = 0; q < 16; q++) y[q] = 0.f;
    for (int p = 0; p < numv; p++) {
        int sv = __shfl(sorted, p);
        float val = voxelwise[sv*64 + lane];
        const float* w = &W1L[g*257 + p];
#pragma unroll
        for (int q = 0; q < 16; q++) y[q] += val * w[q*16];
    }
#pragma unroll
    for (int q = 0; q < 16; q++) {
        float yy = y[q] * fold[592 + g*16 + q] + fold[848 + g*16 + q];
        yy = mishf(yy);
        y[q] = (q < numv) ? yy : 0.f;
    }

    // bfe2: z[c] = sum_p y[p]*W2[g][c][p]
    float z0 = 0.f, z1 = 0.f;
#pragma unroll
    for (int p = 0; p < 16; p++) {
        z0 += y[p] * W2L[g*33 + p];
        z1 += y[p] * W2L[g*33 + 16 + p];
    }
    z0 = mishf(z0 * fold[1104 + g*2 + 0] + fold[1136 + g*2 + 0]);
    z1 = mishf(z1 * fold[1104 + g*2 + 1] + fold[1136 + g*2 + 1]);

    int k0 = ii*32 + g*2;                        // x17 index = i*32 + g*2 + c
    *(float2*)(x17g + aidx*128 + k0) = make_float2(z0, z1);
}

// ---------------- bfe3 pass 1: x18 = fe(x17 @ W3.T), in-place ----------------
__global__ __launch_bounds__(256, 2) void bfe3_pass(
    const int* __restrict__ nactp, const float* __restrict__ W3,
    const float* __restrict__ fold, float* __restrict__ io)
{
    int tid = blockIdx.x * 256 + threadIdx.x;
    if (tid >= *nactp) return;
    const f32x16* xin = (const f32x16*)(io + tid*128);
    f32x16 xv0 = xin[0], xv1 = xin[1], xv2 = xin[2], xv3 = xin[3];
    f32x16 xv4 = xin[4], xv5 = xin[5], xv6 = xin[6], xv7 = xin[7];
#pragma unroll 2
    for (int o = 0; o < 128; o++) {
        const float* wr = W3 + o*128;
        float y0 = 0.f, y1 = 0.f, y2 = 0.f, y3 = 0.f;
#pragma unroll
        for (int k = 0; k < 16; k++) {
            y0 += xv0[k] * wr[k]      + xv1[k] * wr[16+k];
            y1 += xv2[k] * wr[32+k]   + xv3[k] * wr[48+k];
            y2 += xv4[k] * wr[64+k]   + xv5[k] * wr[80+k];
            y3 += xv6[k] * wr[96+k]   + xv7[k] * wr[112+k];
        }
        float y = ((y0+y1) + (y2+y3)) * fold[336+o] + fold[464+o];
        io[tid*128 + o] = mishf(y);
    }
}

// ---------------- bfe3 pass 2: x19 + scatter to out[c][w][h] ----------------
__global__ __launch_bounds__(256, 2) void bfe3_out(
    const int* __restrict__ nactp, const int* __restrict__ act,
    const float* __restrict__ W3, const float* __restrict__ fold,
    const float* __restrict__ x18g, float* __restrict__ out)
{
    int tid = blockIdx.x * 256 + threadIdx.x;
    if (tid >= *nactp) return;
    const f32x16* xin = (const f32x16*)(x18g + tid*128);
    f32x16 xv0 = xin[0], xv1 = xin[1], xv2 = xin[2], xv3 = xin[3];
    f32x16 xv4 = xin[4], xv5 = xin[5], xv6 = xin[6], xv7 = xin[7];
    int cell = act[tid];
    int h = cell / BEVW;
    int w = cell - h * BEVW;
    float* op = out + w*BEVH + h;
#pragma unroll 2
    for (int o = 0; o < 128; o++) {
        const float* wr = W3 + o*128;
        float y0 = 0.f, y1 = 0.f, y2 = 0.f, y3 = 0.f;
#pragma unroll
        for (int k = 0; k < 16; k++) {
            y0 += xv0[k] * wr[k]      + xv1[k] * wr[16+k];
            y1 += xv2[k] * wr[32+k]   + xv3[k] * wr[48+k];
            y2 += xv4[k] * wr[64+k]   + xv5[k] * wr[80+k];
            y3 += xv6[k] * wr[96+k]   + xv7[k] * wr[112+k];
        }
        float y = ((y0+y1) + (y2+y3)) * fold[336+o] + fold[464+o];
        op[o * NCELL] = mishf(y);
    }
}

extern "C" void kernel_launch(void* const* d_in, const int* in_sizes, int n_in,
                              void* d_out, int out_size, void* d_ws, size_t ws_size,
                              hipStream_t stream) {
    const float* features = (const float*)d_in[0];
    const int*   coors    = (const int*)d_in[1];
    const int*   num_vox  = (const int*)d_in[2];
    const float* vfe1_W   = (const float*)d_in[3];
    const float* vfe1_bn  = (const float*)d_in[4];
    const float* vfe2_W   = (const float*)d_in[5];
    const float* vfe2_bn  = (const float*)d_in[6];
    const float* vfe3_W   = (const float*)d_in[7];
    const float* vfe3_bn  = (const float*)d_in[8];
    const float* vfe4_W   = (const float*)d_in[9];
    const float* vfe4_bn  = (const float*)d_in[10];
    const float* bfe1_W   = (const float*)d_in[11];
    const float* bfe1_bn  = (const float*)d_in[12];
    const float* bfe2_W   = (const float*)d_in[13];
    const float* bfe2_bn  = (const float*)d_in[14];
    const float* bfe3_W   = (const float*)d_in[15];
    const float* bfe3_bn  = (const float*)d_in[16];
    float* out = (float*)d_out;

    char* ws = (char*)d_ws;
    int*   nact      = (int*)ws;
    int*   cnt       = (int*)(ws + 256);
    int*   list      = (int*)(ws + 857600);
    float* voxelwise = (float*)(ws + 14571008);
    int*   act       = (int*)(ws + 24811008);
    float* x17g      = (float*)(ws + 24971008);
    float* fold      = (float*)(ws + 45451008);
    float* w4t       = (float*)(ws + 45455680);

    hipMemsetAsync(ws, 0, 857600, stream);                       // nact + cnt
    hipMemsetAsync(d_out, 0, (size_t)out_size * sizeof(float), stream);

    setup_kernel<<<1, 256, 0, stream>>>(vfe1_bn, vfe2_bn, vfe3_bn, vfe4_bn,
                                        bfe1_bn, bfe2_bn, bfe3_bn, vfe4_W,
                                        fold, w4t);
    vfe_kernel<<<NVOX/8, 256, 0, stream>>>(features, coors, num_vox,
                                           vfe1_W, vfe2_W, vfe3_W, w4t, fold,
                                           voxelwise, cnt, list, nact, act);
    bfe_front<<<NVOX/4, 256, 0, stream>>>(nact, act, cnt, list, voxelwise,
                                          bfe1_W, bfe2_W, fold, x17g);
    bfe3_pass<<<(NVOX+255)/256, 256, 0, stream>>>(nact, bfe3_W, fold, x17g);
    bfe3_out<<<(NVOX+255)/256, 256, 0, stream>>>(nact, act, bfe3_W, fold, x17g, out);
}

// Round 4
// 906.419 us; speedup vs baseline: 1.6789x; 1.6789x over previous
//
#include <hip/hip_runtime.h>

#define BEVW 432
#define BEVH 496
#define NCELL (BEVW*BEVH)      // 214272
#define NVOX  40000
#define EPSB  1e-5f

// ---- repeat macros (token-pasted literal indices; no arrays anywhere) ----
#define REP8_0(M)  M(0) M(1) M(2) M(3) M(4) M(5) M(6) M(7)
#define REP8_8(M)  M(8) M(9) M(10) M(11) M(12) M(13) M(14) M(15)
#define REP8_16(M) M(16) M(17) M(18) M(19) M(20) M(21) M(22) M(23)
#define REP8_24(M) M(24) M(25) M(26) M(27) M(28) M(29) M(30) M(31)
#define REP16_0(M) REP8_0(M) REP8_8(M)
#define REP32_0(M) REP16_0(M) REP8_16(M) REP8_24(M)
#define REP8_32(M) M(32) M(33) M(34) M(35) M(36) M(37) M(38) M(39)
#define REP8_40(M) M(40) M(41) M(42) M(43) M(44) M(45) M(46) M(47)
#define REP8_48(M) M(48) M(49) M(50) M(51) M(52) M(53) M(54) M(55)
#define REP8_56(M) M(56) M(57) M(58) M(59) M(60) M(61) M(62) M(63)
#define REP32_32(M) REP8_32(M) REP8_40(M) REP8_48(M) REP8_56(M)
#define REP64_0(M) REP32_0(M) REP32_32(M)
#define REP32_64(M) M(64) M(65) M(66) M(67) M(68) M(69) M(70) M(71) \
  M(72) M(73) M(74) M(75) M(76) M(77) M(78) M(79) M(80) M(81) M(82) M(83) \
  M(84) M(85) M(86) M(87) M(88) M(89) M(90) M(91) M(92) M(93) M(94) M(95)
#define REP32_96(M) M(96) M(97) M(98) M(99) M(100) M(101) M(102) M(103) \
  M(104) M(105) M(106) M(107) M(108) M(109) M(110) M(111) M(112) M(113) \
  M(114) M(115) M(116) M(117) M(118) M(119) M(120) M(121) M(122) M(123) \
  M(124) M(125) M(126) M(127)
#define REP128_0(M) REP64_0(M) REP32_64(M) REP32_96(M)

// ---------------- workspace layout (bytes) ----------------
// 0        : int nact (zeroed) | 256: int cnt[NCELL] (zeroed)
// 857600   : int list[NCELL*16]
// 14571008 : float voxelwise[NVOX*64]
// 24811008 : int act[NVOX]
// 24971008 : float x17g[NVOX*128]
// 45451008 : float fold[1168]
// 45455680 : float w4t[4096]

__device__ __forceinline__ float mishf(float y) {
    float e = __expf(fminf(y, 40.f));
    float n = e * (e + 2.f);
    return y * n * __builtin_amdgcn_rcpf(n + 2.f);
}

#define WMAX32(a) { a = fmaxf(a, __shfl_xor(a, 16)); a = fmaxf(a, __shfl_xor(a, 8)); \
                    a = fmaxf(a, __shfl_xor(a, 4));  a = fmaxf(a, __shfl_xor(a, 2)); \
                    a = fmaxf(a, __shfl_xor(a, 1)); }

__device__ __forceinline__ float finpool(float acc, float base, float s, float tf, float maskf) {
    float y = acc * s + tf;
    y = mishf(y) * maskf + base;
    WMAX32(y);
    return y;
}

// fold layout: vfe1 s@0 t@8 | vfe2 s@16 t@48 | vfe3 s@80 t@144 | vfe4 s@208 t@272
// bfe3 s@336 t@464 | bfe1 s@592 t@848 | bfe2 s@1104 t@1136
__global__ __launch_bounds__(256) void setup_kernel(
    const float* __restrict__ vbn1, const float* __restrict__ vbn2,
    const float* __restrict__ vbn3, const float* __restrict__ vbn4,
    const float* __restrict__ bbn1, const float* __restrict__ bbn2,
    const float* __restrict__ bbn3, const float* __restrict__ W4,
    float* __restrict__ fold, float* __restrict__ w4t)
{
    int tid = threadIdx.x;
    if (tid < 8)  { float s = vbn1[tid]/sqrtf(vbn1[24+tid]+EPSB);  fold[tid]      = s; fold[8+tid]   = vbn1[8+tid]  - vbn1[16+tid]*s; }
    if (tid < 32) { float s = vbn2[tid]/sqrtf(vbn2[96+tid]+EPSB);  fold[16+tid]   = s; fold[48+tid]  = vbn2[32+tid] - vbn2[64+tid]*s; }
    if (tid < 64) { float s = vbn3[tid]/sqrtf(vbn3[192+tid]+EPSB); fold[80+tid]   = s; fold[144+tid] = vbn3[64+tid] - vbn3[128+tid]*s; }
    if (tid < 64) { float s = vbn4[tid]/sqrtf(vbn4[192+tid]+EPSB); fold[208+tid]  = s; fold[272+tid] = vbn4[64+tid] - vbn4[128+tid]*s; }
    if (tid < 128){ float s = bbn3[tid]/sqrtf(bbn3[384+tid]+EPSB); fold[336+tid]  = s; fold[464+tid] = bbn3[128+tid]- bbn3[256+tid]*s; }
    { int g = tid >> 4, q = tid & 15;
      const float* b = bbn1 + g*64;
      float s = b[q]/sqrtf(b[48+q]+EPSB);
      fold[592+tid] = s; fold[848+tid] = b[16+q] - b[32+q]*s; }
    if (tid < 32) { int g = tid >> 1, c = tid & 1;
      const float* b = bbn2 + g*8;
      float s = b[c]/sqrtf(b[6+c]+EPSB);
      fold[1104+tid] = s; fold[1136+tid] = b[2+c] - b[4+c]*s; }
    for (int i = tid; i < 4096; i += 256) { int o = i >> 6, c = i & 63; w4t[c*64+o] = W4[i]; }
}

// ---------------- VFE: 8 voxels / block, lane=point, ALL state named scalars ----------
// Rounds 1-3: subscripted locals (arrays AND ext_vectors) stayed allocas -> scratch,
// FETCH 21 GB == x2 re-read per fe3 iter. Named scalars cannot be allocas.
__global__ __launch_bounds__(256, 2) void vfe_kernel(
    const float* __restrict__ feat, const int* __restrict__ coors,
    const int* __restrict__ nvx,
    const float* __restrict__ W1, const float* __restrict__ W2,
    const float* __restrict__ W3, const float* __restrict__ W4T,
    const float* __restrict__ fold,
    float* __restrict__ voxelwise, int* __restrict__ cnt,
    int* __restrict__ list, int* __restrict__ nact, int* __restrict__ act)
{
    int tid = threadIdx.x;
    int v = blockIdx.x * 8 + (tid >> 5);
    int t = tid & 31;

    const float* fp = feat + (v*32 + t)*8;
    float4 fa = *(const float4*)fp;
    float4 fb = *(const float4*)(fp+4);
    int numv = nvx[v];
    float maskf = (t < numv) ? 1.f : 0.f;

    // ---- fe1 (8->8) + pool ----
#define D1(o) float x1_##o; float m1_##o;
    REP8_0(D1)
#undef D1
#define FE1(o) { const float* w = W1 + (o)*8; \
    float ya = fa.x*w[0] + fa.y*w[1]; float yb = fa.z*w[2] + fa.w*w[3]; \
    float yc = fb.x*w[4] + fb.y*w[5]; float yd = fb.z*w[6] + fb.w*w[7]; \
    float yy = ((ya+yb)+(yc+yd)) * fold[(o)] + fold[8+(o)]; \
    x1_##o = mishf(yy); }
    REP8_0(FE1)
#undef FE1
#define P1(o) { float a = x1_##o; WMAX32(a); m1_##o = a; }
    REP8_0(P1)
#undef P1

    // ---- fe2 (16->32) + pool; agg kept unmasked first ----
#define D2(o) float x2_##o; float agg_##o;
    REP32_0(D2)
#undef D2
#define FE2(o) { const float* w = W2 + (o)*16; \
    float ya = x1_0*w[0]+x1_1*w[1]+x1_2*w[2]+x1_3*w[3]; \
    float yb = x1_4*w[4]+x1_5*w[5]+x1_6*w[6]+x1_7*w[7]; \
    float yc = m1_0*w[8]+m1_1*w[9]+m1_2*w[10]+m1_3*w[11]; \
    float yd = m1_4*w[12]+m1_5*w[13]+m1_6*w[14]+m1_7*w[15]; \
    float yy = ((ya+yb)+(yc+yd)) * fold[16+(o)] + fold[48+(o)]; \
    x2_##o = mishf(yy); }
    REP32_0(FE2)
#undef FE2
#define P2(o) { float a = x2_##o; WMAX32(a); agg_##o = a; }
    REP32_0(P2)
#undef P2

    // ---- y_agg: fe3 contribution of the voxel-uniform aggregate half, computed
    // once per voxel: lane t covers rows t and t+32 (2x32 MACs), shared via shfl.
    const float* wa = W3 + t*64 + 32;
    const float* wb = W3 + (t+32)*64 + 32;
    float yagg1 = 0.f, yagg2 = 0.f;
#define YG(j) yagg1 += agg_##j * wa[j]; yagg2 += agg_##j * wb[j];
    REP32_0(YG)
#undef YG

    // ---- apply mask ----
#define MSK(o) x2_##o *= maskf; agg_##o *= maskf;
    REP32_0(MSK)
#undef MSK

    // ---- fe3 (64->64) + incremental fe4 ----
#define ACD(q) float acc_##q = 0.f;
    REP64_0(ACD)
#undef ACD
    for (int o = 0; o < 64; o++) {
        const float* w3r = W3 + o*64;
        float s0=0.f, s1=0.f, s2=0.f, s3=0.f;
#define F3A(c) s0 += x2_##c * w3r[c];
#define F3B(c) s1 += x2_##c * w3r[c];
#define F3C(c) s2 += x2_##c * w3r[c];
#define F3D(c) s3 += x2_##c * w3r[c];
        REP8_0(F3A) REP8_8(F3B) REP8_16(F3C) REP8_24(F3D)
#undef F3A
#undef F3B
#undef F3C
#undef F3D
        float ysrc = (o < 32) ? yagg1 : yagg2;
        float ya = __shfl(ysrc, (o & 31), 32);
        float yy = ((s0+s1)+(s2+s3)) + maskf * ya;
        yy = yy * fold[80+o] + fold[144+o];
        float x3 = mishf(yy);
        const float* w4r = W4T + o*64;
#define F4(q) acc_##q += x3 * w4r[q];
        REP64_0(F4)
#undef F4
    }

    // ---- bn4 + mish + residual + pool, store per quad ----
#define FQ(q0,q1,q2,q3,b0,b1,b2,b3) { \
    float r0 = finpool(acc_##q0, b0, fold[208+q0], fold[272+q0], maskf); \
    float r1 = finpool(acc_##q1, b1, fold[208+q1], fold[272+q1], maskf); \
    float r2 = finpool(acc_##q2, b2, fold[208+q2], fold[272+q2], maskf); \
    float r3 = finpool(acc_##q3, b3, fold[208+q3], fold[272+q3], maskf); \
    if (t == 0) *(float4*)(voxelwise + v*64 + q0) = make_float4(r0,r1,r2,r3); }
    FQ(0,1,2,3,     x2_0,x2_1,x2_2,x2_3)
    FQ(4,5,6,7,     x2_4,x2_5,x2_6,x2_7)
    FQ(8,9,10,11,   x2_8,x2_9,x2_10,x2_11)
    FQ(12,13,14,15, x2_12,x2_13,x2_14,x2_15)
    FQ(16,17,18,19, x2_16,x2_17,x2_18,x2_19)
    FQ(20,21,22,23, x2_20,x2_21,x2_22,x2_23)
    FQ(24,25,26,27, x2_24,x2_25,x2_26,x2_27)
    FQ(28,29,30,31, x2_28,x2_29,x2_30,x2_31)
    FQ(32,33,34,35, agg_0,agg_1,agg_2,agg_3)
    FQ(36,37,38,39, agg_4,agg_5,agg_6,agg_7)
    FQ(40,41,42,43, agg_8,agg_9,agg_10,agg_11)
    FQ(44,45,46,47, agg_12,agg_13,agg_14,agg_15)
    FQ(48,49,50,51, agg_16,agg_17,agg_18,agg_19)
    FQ(52,53,54,55, agg_20,agg_21,agg_22,agg_23)
    FQ(56,57,58,59, agg_24,agg_25,agg_26,agg_27)
    FQ(60,61,62,63, agg_28,agg_29,agg_30,agg_31)
#undef FQ

    if (t == 0) {
        int cell = coors[v*2] * BEVW + coors[v*2+1];
        int pos = atomicAdd(&cnt[cell], 1);
        if (pos < 16) list[cell*16 + pos] = v;
        if (pos == 0) { int k = atomicAdd(nact, 1); act[k] = cell; }
    }
}

// ---------------- BFE front (bfe1+bfe2): 1 wave = 1 active cell ----------------
__global__ __launch_bounds__(256) void bfe_front(
    const int* __restrict__ nact, const int* __restrict__ act,
    const int* __restrict__ cnt, const int* __restrict__ list,
    const float* __restrict__ voxelwise,
    const float* __restrict__ W1g, const float* __restrict__ W2g,
    const float* __restrict__ fold, float* __restrict__ x17g)
{
    __shared__ float W1L[16*257];
    __shared__ float W2L[16*33];
    for (int i = threadIdx.x; i < 4096; i += 256) W1L[(i>>8)*257 + (i&255)] = W1g[i];
    for (int i = threadIdx.x; i < 512;  i += 256) W2L[(i>>5)*33  + (i&31)]  = W2g[i];
    __syncthreads();

    int n_act = *nact;
    int aidx = blockIdx.x * 4 + (threadIdx.x >> 6);
    if (aidx >= n_act) return;

    int lane = threadIdx.x & 63;
    int g = lane >> 2, ii = lane & 3;
    int cell = act[aidx];
    int numv = min(cnt[cell], 16);

    int myidx = (lane < numv) ? list[cell*16 + lane] : (0x40000000 + lane);
    int rank = 0;
    for (int j = 0; j < numv; j++) { int vj = __shfl(myidx, j); rank += (vj < myidx) ? 1 : 0; }
    if (lane >= numv) rank = lane;
    int sorted = __builtin_amdgcn_ds_permute(rank << 2, myidx);

#define YD(q) float y_##q = 0.f;
    REP16_0(YD)
#undef YD
    for (int p = 0; p < numv; p++) {
        int sv = __shfl(sorted, p);
        float val = voxelwise[sv*64 + lane];
        const float* w = &W1L[g*257 + p];
#define BF1(q) y_##q += val * w[(q)*16];
        REP16_0(BF1)
#undef BF1
    }
#define BN1(q) { float yy = y_##q * fold[592 + g*16 + (q)] + fold[848 + g*16 + (q)]; \
    yy = mishf(yy); y_##q = ((q) < numv) ? yy : 0.f; }
    REP16_0(BN1)
#undef BN1

    float z0 = 0.f, z1 = 0.f;
#define BF2(p) z0 += y_##p * W2L[g*33 + (p)]; z1 += y_##p * W2L[g*33 + 16 + (p)];
    REP16_0(BF2)
#undef BF2
    z0 = mishf(z0 * fold[1104 + g*2 + 0] + fold[1136 + g*2 + 0]);
    z1 = mishf(z1 * fold[1104 + g*2 + 1] + fold[1136 + g*2 + 1]);

    int k0 = ii*32 + g*2;
    *(float2*)(x17g + aidx*128 + k0) = make_float2(z0, z1);
}

// ---------------- bfe3 pass 1: x18 = fe(x17 @ W3.T), in-place ----------------
__global__ __launch_bounds__(256, 2) void bfe3_pass(
    const int* __restrict__ nactp, const float* __restrict__ W3,
    const float* __restrict__ fold, float* __restrict__ io)
{
    int tid = blockIdx.x * 256 + threadIdx.x;
    if (tid >= *nactp) return;
    const float* xp = io + tid*128;
#define XD(i) float x_##i = xp[(i)];
    REP128_0(XD)
#undef XD
    for (int o = 0; o < 128; o++) {
        const float* wr = W3 + o*128;
        float s0=0.f, s1=0.f, s2=0.f, s3=0.f;
#define DA(c) s0 += x_##c * wr[c];
#define DB(c) s1 += x_##c * wr[c];
#define DC(c) s2 += x_##c * wr[c];
#define DD(c) s3 += x_##c * wr[c];
        REP32_0(DA) REP32_32(DB) REP32_64(DC) REP32_96(DD)
#undef DA
#undef DB
#undef DC
#undef DD
        float yy = ((s0+s1)+(s2+s3)) * fold[336+o] + fold[464+o];
        io[tid*128 + o] = mishf(yy);
    }
}

// ---------------- bfe3 pass 2: x19 + scatter to out[c][w][h] ----------------
__global__ __launch_bounds__(256, 2) void bfe3_out(
    const int* __restrict__ nactp, const int* __restrict__ act,
    const float* __restrict__ W3, const float* __restrict__ fold,
    const float* __restrict__ x18g, float* __restrict__ out)
{
    int tid = blockIdx.x * 256 + threadIdx.x;
    if (tid >= *nactp) return;
    const float* xp = x18g + tid*128;
#define XE(i) float x_##i = xp[(i)];
    REP128_0(XE)
#undef XE
    int cell = act[tid];
    int h = cell / BEVW;
    int w = cell - h * BEVW;
    float* op = out + w*BEVH + h;
    for (int o = 0; o < 128; o++) {
        const float* wr = W3 + o*128;
        float s0=0.f, s1=0.f, s2=0.f, s3=0.f;
#define EA(c) s0 += x_##c * wr[c];
#define EB(c) s1 += x_##c * wr[c];
#define EC(c) s2 += x_##c * wr[c];
#define ED(c) s3 += x_##c * wr[c];
        REP32_0(EA) REP32_32(EB) REP32_64(EC) REP32_96(ED)
#undef EA
#undef EB
#undef EC
#undef ED
        float yy = ((s0+s1)+(s2+s3)) * fold[336+o] + fold[464+o];
        op[o * NCELL] = mishf(yy);
    }
}

extern "C" void kernel_launch(void* const* d_in, const int* in_sizes, int n_in,
                              void* d_out, int out_size, void* d_ws, size_t ws_size,
                              hipStream_t stream) {
    const float* features = (const float*)d_in[0];
    const int*   coors    = (const int*)d_in[1];
    const int*   num_vox  = (const int*)d_in[2];
    const float* vfe1_W   = (const float*)d_in[3];
    const float* vfe2_W   = (const float*)d_in[5];
    const float* vfe3_W   = (const float*)d_in[7];
    const float* vfe4_W   = (const float*)d_in[9];
    const float* bfe1_W   = (const float*)d_in[11];
    const float* bfe2_W   = (const float*)d_in[13];
    const float* bfe3_W   = (const float*)d_in[15];
    const float* vfe1_bn  = (const float*)d_in[4];
    const float* vfe2_bn  = (const float*)d_in[6];
    const float* vfe3_bn  = (const float*)d_in[8];
    const float* vfe4_bn  = (const float*)d_in[10];
    const float* bfe1_bn  = (const float*)d_in[12];
    const float* bfe2_bn  = (const float*)d_in[14];
    const float* bfe3_bn  = (const float*)d_in[16];
    float* out = (float*)d_out;

    char* ws = (char*)d_ws;
    int*   nact      = (int*)ws;
    int*   cnt       = (int*)(ws + 256);
    int*   list      = (int*)(ws + 857600);
    float* voxelwise = (float*)(ws + 14571008);
    int*   act       = (int*)(ws + 24811008);
    float* x17g      = (float*)(ws + 24971008);
    float* fold      = (float*)(ws + 45451008);
    float* w4t       = (float*)(ws + 45455680);

    hipMemsetAsync(ws, 0, 857600, stream);
    hipMemsetAsync(d_out, 0, (size_t)out_size * sizeof(float), stream);

    setup_kernel<<<1, 256, 0, stream>>>(vfe1_bn, vfe2_bn, vfe3_bn, vfe4_bn,
                                        bfe1_bn, bfe2_bn, bfe3_bn, vfe4_W,
                                        fold, w4t);
    vfe_kernel<<<NVOX/8, 256, 0, stream>>>(features, coors, num_vox,
                                           vfe1_W, vfe2_W, vfe3_W, w4t, fold,
                                           voxelwise, cnt, list, nact, act);
    bfe_front<<<NVOX/4, 256, 0, stream>>>(nact, act, cnt, list, voxelwise,
                                          bfe1_W, bfe2_W, fold, x17g);
    bfe3_pass<<<(NVOX+255)/256, 256, 0, stream>>>(nact, bfe3_W, fold, x17g);
    bfe3_out<<<(NVOX+255)/256, 256, 0, stream>>>(nact, act, bfe3_W, fold, x17g, out);
}

// Round 5
// 873.649 us; speedup vs baseline: 1.7419x; 1.0375x over previous
//
#include <hip/hip_runtime.h>

#define BEVW 432
#define BEVH 496
#define NCELL (BEVW*BEVH)      // 214272
#define NVOX  40000
#define EPSB  1e-5f

// ---- repeat macros (token-pasted literal indices) ----
#define REP8_0(M)  M(0) M(1) M(2) M(3) M(4) M(5) M(6) M(7)
#define REP8_8(M)  M(8) M(9) M(10) M(11) M(12) M(13) M(14) M(15)
#define REP8_16(M) M(16) M(17) M(18) M(19) M(20) M(21) M(22) M(23)
#define REP8_24(M) M(24) M(25) M(26) M(27) M(28) M(29) M(30) M(31)
#define REP8_32(M) M(32) M(33) M(34) M(35) M(36) M(37) M(38) M(39)
#define REP8_40(M) M(40) M(41) M(42) M(43) M(44) M(45) M(46) M(47)
#define REP8_48(M) M(48) M(49) M(50) M(51) M(52) M(53) M(54) M(55)
#define REP8_56(M) M(56) M(57) M(58) M(59) M(60) M(61) M(62) M(63)
#define REP16_0(M)  REP8_0(M)  REP8_8(M)
#define REP16_16(M) REP8_16(M) REP8_24(M)
#define REP16_32(M) REP8_32(M) REP8_40(M)
#define REP16_48(M) REP8_48(M) REP8_56(M)
#define REP32_0(M) REP16_0(M) REP16_16(M)

// ---------------- workspace layout (bytes) ----------------
// 0        : int nact (zeroed) | 256: int cnt[NCELL] (zeroed)
// 857600   : int list[NCELL*16]
// 14571008 : float voxelwise[NVOX*64]
// 24811008 : int act[NVOX]
// 24971008 : float x17g[NVOX*128]
// 45451008 : float fold[1168]
// 45455680 : float w4t[4096]

__device__ __forceinline__ float mishf(float y) {
    float e = __expf(fminf(y, 40.f));
    float n = e * (e + 2.f);
    return y * n * __builtin_amdgcn_rcpf(n + 2.f);
}

#define WMAX32(a) { a = fmaxf(a, __shfl_xor(a, 16)); a = fmaxf(a, __shfl_xor(a, 8)); \
                    a = fmaxf(a, __shfl_xor(a, 4));  a = fmaxf(a, __shfl_xor(a, 2)); \
                    a = fmaxf(a, __shfl_xor(a, 1)); }

__device__ __forceinline__ float finpool(float acc, float base, float s, float tf, float maskf) {
    float y = acc * s + tf;
    y = mishf(y) * maskf + base;
    WMAX32(y);
    return y;
}

// fold layout: vfe1 s@0 t@8 | vfe2 s@16 t@48 | vfe3 s@80 t@144 | vfe4 s@208 t@272
// bfe3 s@336 t@464 | bfe1 s@592 t@848 | bfe2 s@1104 t@1136
__global__ __launch_bounds__(256) void setup_kernel(
    const float* __restrict__ vbn1, const float* __restrict__ vbn2,
    const float* __restrict__ vbn3, const float* __restrict__ vbn4,
    const float* __restrict__ bbn1, const float* __restrict__ bbn2,
    const float* __restrict__ bbn3, const float* __restrict__ W4,
    float* __restrict__ fold, float* __restrict__ w4t)
{
    int tid = threadIdx.x;
    if (tid < 8)  { float s = vbn1[tid]/sqrtf(vbn1[24+tid]+EPSB);  fold[tid]      = s; fold[8+tid]   = vbn1[8+tid]  - vbn1[16+tid]*s; }
    if (tid < 32) { float s = vbn2[tid]/sqrtf(vbn2[96+tid]+EPSB);  fold[16+tid]   = s; fold[48+tid]  = vbn2[32+tid] - vbn2[64+tid]*s; }
    if (tid < 64) { float s = vbn3[tid]/sqrtf(vbn3[192+tid]+EPSB); fold[80+tid]   = s; fold[144+tid] = vbn3[64+tid] - vbn3[128+tid]*s; }
    if (tid < 64) { float s = vbn4[tid]/sqrtf(vbn4[192+tid]+EPSB); fold[208+tid]  = s; fold[272+tid] = vbn4[64+tid] - vbn4[128+tid]*s; }
    if (tid < 128){ float s = bbn3[tid]/sqrtf(bbn3[384+tid]+EPSB); fold[336+tid]  = s; fold[464+tid] = bbn3[128+tid]- bbn3[256+tid]*s; }
    { int g = tid >> 4, q = tid & 15;
      const float* b = bbn1 + g*64;
      float s = b[q]/sqrtf(b[48+q]+EPSB);
      fold[592+tid] = s; fold[848+tid] = b[16+q] - b[32+q]*s; }
    if (tid < 32) { int g = tid >> 1, c = tid & 1;
      const float* b = bbn2 + g*8;
      float s = b[c]/sqrtf(b[6+c]+EPSB);
      fold[1104+tid] = s; fold[1136+tid] = b[2+c] - b[4+c]*s; }
    for (int i = tid; i < 4096; i += 256) { int o = i >> 6, c = i & 63; w4t[c*64+o] = W4[i]; }
}

// ---------------- VFE: 4 voxels / 128-thr block, lane=point ----------------
// x3 routed through XOR-swizzled LDS so fe4 accumulates in 4 chunks of 16:
// peak live ~90 floats -> no AGPR round-trips (round-4: acc64+x2 64 -> churn).
__global__ __launch_bounds__(128, 3) void vfe_kernel(
    const float* __restrict__ feat, const int* __restrict__ coors,
    const int* __restrict__ nvx,
    const float* __restrict__ W1, const float* __restrict__ W2,
    const float* __restrict__ W3, const float* __restrict__ W4T,
    const float* __restrict__ fold,
    float* __restrict__ voxelwise, int* __restrict__ cnt,
    int* __restrict__ list, int* __restrict__ nact, int* __restrict__ act)
{
    __shared__ float x3L[128*64];     // 32 KB; per-thread row of 64, XOR-swizzled
    int tid = threadIdx.x;
    int v = blockIdx.x * 4 + (tid >> 5);
    int t = tid & 31;
    float* x3me = x3L + tid*64;

    const float* fp = feat + (v*32 + t)*8;
    float4 fa = *(const float4*)fp;
    float4 fb = *(const float4*)(fp+4);
    int numv = nvx[v];
    float maskf = (t < numv) ? 1.f : 0.f;

    // ---- fe1 (8->8) + pool ----
#define D1(o) float x1_##o; float m1_##o;
    REP8_0(D1)
#undef D1
#define FE1(o) { const float* w = W1 + (o)*8; \
    float ya = fa.x*w[0] + fa.y*w[1]; float yb = fa.z*w[2] + fa.w*w[3]; \
    float yc = fb.x*w[4] + fb.y*w[5]; float yd = fb.z*w[6] + fb.w*w[7]; \
    float yy = ((ya+yb)+(yc+yd)) * fold[(o)] + fold[8+(o)]; \
    x1_##o = mishf(yy); }
    REP8_0(FE1)
#undef FE1
#define P1(o) { float a = x1_##o; WMAX32(a); m1_##o = a; }
    REP8_0(P1)
#undef P1

    // ---- fe2 (16->32) + pool ----
#define D2(o) float x2_##o; float agg_##o;
    REP32_0(D2)
#undef D2
#define FE2(o) { const float* w = W2 + (o)*16; \
    float ya = x1_0*w[0]+x1_1*w[1]+x1_2*w[2]+x1_3*w[3]; \
    float yb = x1_4*w[4]+x1_5*w[5]+x1_6*w[6]+x1_7*w[7]; \
    float yc = m1_0*w[8]+m1_1*w[9]+m1_2*w[10]+m1_3*w[11]; \
    float yd = m1_4*w[12]+m1_5*w[13]+m1_6*w[14]+m1_7*w[15]; \
    float yy = ((ya+yb)+(yc+yd)) * fold[16+(o)] + fold[48+(o)]; \
    x2_##o = mishf(yy); }
    REP32_0(FE2)
#undef FE2
#define P2(o) { float a = x2_##o; WMAX32(a); agg_##o = a; }
    REP32_0(P2)
#undef P2

    // ---- yagg: fe3 contribution of the voxel-uniform aggregate half ----
    const float* wa = W3 + t*64 + 32;
    const float* wb = W3 + (t+32)*64 + 32;
    float yagg1 = 0.f, yagg2 = 0.f;
#define YG(j) yagg1 += agg_##j * wa[j]; yagg2 += agg_##j * wb[j];
    REP32_0(YG)
#undef YG

#define MSK(o) x2_##o *= maskf; agg_##o *= maskf;
    REP32_0(MSK)
#undef MSK

    // ---- fe3 (64->64): x3 -> LDS (bank = (o^t)&31, conflict-free) ----
    for (int o = 0; o < 64; o++) {
        const float* w3r = W3 + o*64;
        float s0=0.f, s1=0.f, s2=0.f, s3=0.f;
#define F3A(c) s0 += x2_##c * w3r[c];
#define F3B(c) s1 += x2_##c * w3r[c];
#define F3C(c) s2 += x2_##c * w3r[c];
#define F3D(c) s3 += x2_##c * w3r[c];
        REP8_0(F3A) REP8_8(F3B) REP8_16(F3C) REP8_24(F3D)
#undef F3A
#undef F3B
#undef F3C
#undef F3D
        float ysrc = (o < 32) ? yagg1 : yagg2;
        float ya = __shfl(ysrc, (o & 31), 32);
        float yy = ((s0+s1)+(s2+s3)) + maskf * ya;
        yy = yy * fold[80+o] + fold[144+o];
        x3me[o ^ t] = mishf(yy);
    }

    // ---- fe4 in 4 chunks of 16 accs + finpool + store ----
#define DECLA(q) float a_##q = 0.f;
#define FMA_A(q) a_##q += x3v * w4r[q];
#define FQ(q0,q1,q2,q3,b0,b1,b2,b3) { \
    float r0 = finpool(a_##q0, b0, fold[208+q0], fold[272+q0], maskf); \
    float r1 = finpool(a_##q1, b1, fold[208+q1], fold[272+q1], maskf); \
    float r2 = finpool(a_##q2, b2, fold[208+q2], fold[272+q2], maskf); \
    float r3 = finpool(a_##q3, b3, fold[208+q3], fold[272+q3], maskf); \
    if (t == 0) *(float4*)(voxelwise + v*64 + q0) = make_float4(r0,r1,r2,r3); }

    { // chunk 0: q 0..15, residual x2_0..15
        REP16_0(DECLA)
        for (int o = 0; o < 64; o++) { float x3v = x3me[o ^ t]; const float* w4r = W4T + o*64; REP16_0(FMA_A) }
        FQ(0,1,2,3,     x2_0,x2_1,x2_2,x2_3)
        FQ(4,5,6,7,     x2_4,x2_5,x2_6,x2_7)
        FQ(8,9,10,11,   x2_8,x2_9,x2_10,x2_11)
        FQ(12,13,14,15, x2_12,x2_13,x2_14,x2_15)
    }
    { // chunk 1: q 16..31, residual x2_16..31
        REP16_16(DECLA)
        for (int o = 0; o < 64; o++) { float x3v = x3me[o ^ t]; const float* w4r = W4T + o*64; REP16_16(FMA_A) }
        FQ(16,17,18,19, x2_16,x2_17,x2_18,x2_19)
        FQ(20,21,22,23, x2_20,x2_21,x2_22,x2_23)
        FQ(24,25,26,27, x2_24,x2_25,x2_26,x2_27)
        FQ(28,29,30,31, x2_28,x2_29,x2_30,x2_31)
    }
    { // chunk 2: q 32..47, residual agg_0..15
        REP16_32(DECLA)
        for (int o = 0; o < 64; o++) { float x3v = x3me[o ^ t]; const float* w4r = W4T + o*64; REP16_32(FMA_A) }
        FQ(32,33,34,35, agg_0,agg_1,agg_2,agg_3)
        FQ(36,37,38,39, agg_4,agg_5,agg_6,agg_7)
        FQ(40,41,42,43, agg_8,agg_9,agg_10,agg_11)
        FQ(44,45,46,47, agg_12,agg_13,agg_14,agg_15)
    }
    { // chunk 3: q 48..63, residual agg_16..31
        REP16_48(DECLA)
        for (int o = 0; o < 64; o++) { float x3v = x3me[o ^ t]; const float* w4r = W4T + o*64; REP16_48(FMA_A) }
        FQ(48,49,50,51, agg_16,agg_17,agg_18,agg_19)
        FQ(52,53,54,55, agg_20,agg_21,agg_22,agg_23)
        FQ(56,57,58,59, agg_24,agg_25,agg_26,agg_27)
        FQ(60,61,62,63, agg_28,agg_29,agg_30,agg_31)
    }
#undef DECLA
#undef FMA_A
#undef FQ

    if (t == 0) {
        int cell = coors[v*2] * BEVW + coors[v*2+1];
        int pos = atomicAdd(&cnt[cell], 1);
        if (pos < 16) list[cell*16 + pos] = v;
        if (pos == 0) { int k = atomicAdd(nact, 1); act[k] = cell; }
    }
}

// ---------------- BFE front: 1 wave = 1 cell; weights direct from L1 ----------------
__global__ __launch_bounds__(256) void bfe_front(
    const int* __restrict__ nact, const int* __restrict__ act,
    const int* __restrict__ cnt, const int* __restrict__ list,
    const float* __restrict__ voxelwise,
    const float* __restrict__ W1g, const float* __restrict__ W2g,
    const float* __restrict__ fold, float* __restrict__ x17g)
{
    int n_act = *nact;
    int aidx = blockIdx.x * 4 + (threadIdx.x >> 6);
    if (aidx >= n_act) return;

    int lane = threadIdx.x & 63;
    int g = lane >> 2, ii = lane & 3;
    int cell = act[aidx];
    int numv = min(cnt[cell], 16);

    int myidx = (lane < numv) ? list[cell*16 + lane] : (0x40000000 + lane);
    int rank = 0;
    for (int j = 0; j < numv; j++) { int vj = __shfl(myidx, j); rank += (vj < myidx) ? 1 : 0; }
    if (lane >= numv) rank = lane;
    int sorted = __builtin_amdgcn_ds_permute(rank << 2, myidx);

#define YD(q) float y_##q = 0.f;
    REP16_0(YD)
#undef YD
    for (int p = 0; p < numv; p++) {
        int sv = __shfl(sorted, p);
        float val = voxelwise[sv*64 + lane];
        const float* w = W1g + g*256 + p;
#define BF1(q) y_##q += val * w[(q)*16];
        REP16_0(BF1)
#undef BF1
    }
#define BN1(q) { float yy = y_##q * fold[592 + g*16 + (q)] + fold[848 + g*16 + (q)]; \
    yy = mishf(yy); y_##q = ((q) < numv) ? yy : 0.f; }
    REP16_0(BN1)
#undef BN1

    float z0 = 0.f, z1 = 0.f;
#define BF2(p) z0 += y_##p * W2g[g*32 + (p)]; z1 += y_##p * W2g[g*32 + 16 + (p)];
    REP16_0(BF2)
#undef BF2
    z0 = mishf(z0 * fold[1104 + g*2 + 0] + fold[1136 + g*2 + 0]);
    z1 = mishf(z1 * fold[1104 + g*2 + 1] + fold[1136 + g*2 + 1]);

    int k0 = ii*32 + g*2;
    *(float2*)(x17g + aidx*128 + k0) = make_float2(z0, z1);
}

// ---------------- bfe3 fused (x18 and x19): GEMM-shaped ----------------
// 512-thr block = 64 cells; X & X18 tiles in 64 KB swizzled LDS; wave w owns
// output rows w*16..w*16+15 (wave-uniform -> weights via s_load); acc=16/lane.
__global__ __launch_bounds__(512, 1) void bfe3_fused(
    const int* __restrict__ nactp, const int* __restrict__ act,
    const float* __restrict__ W3, const float* __restrict__ fold,
    const float* __restrict__ x17g, float* __restrict__ out)
{
    __shared__ float XL[64*128];   // float4-chunk XOR swizzle: chunk kc at kc^(c&31)
    __shared__ float YL[64*128];
    int tid = threadIdx.x;
    int n_act = *nactp;
    int cb = blockIdx.x * 64;

    // stage x17 tile (coalesced float4 reads; inactive cells -> 0)
    for (int i = tid; i < 64*32; i += 512) {
        int c = i >> 5, kc = i & 31;
        float4 val = (cb + c < n_act) ? ((const float4*)x17g)[(size_t)(cb+c)*32 + kc]
                                      : make_float4(0.f,0.f,0.f,0.f);
        ((float4*)XL)[c*32 + (kc ^ (c & 31))] = val;
    }
    __syncthreads();

    int wv = __builtin_amdgcn_readfirstlane(tid >> 6);   // wave id 0..7
    int c  = tid & 63;
    int ob = wv * 16;                                    // my 16 output rows
    int cswz = c & 31;
    const float4* xrow = (const float4*)XL + c*32;
    const float4* W4p = (const float4*)W3;

    // ---- pass 1: x18 = fe(x17 @ W3.T) -> YL ----
#define DECLB(q) float a_##q = 0.f;
#define ACCB(q) { float4 wq = W4p[(ob+(q))*32 + kc]; \
    a_##q += xv.x*wq.x + xv.y*wq.y + xv.z*wq.z + xv.w*wq.w; }
#define ACTB(q) { float yy = a_##q * fold[336+ob+(q)] + fold[464+ob+(q)]; a_##q = mishf(yy); }
    {
        REP16_0(DECLB)
        for (int kc = 0; kc < 32; kc++) {
            float4 xv = xrow[kc ^ cswz];
            REP16_0(ACCB)
        }
        REP16_0(ACTB)
        ((float4*)YL)[c*32 + ((wv*4 + 0) ^ cswz)] = make_float4(a_0,  a_1,  a_2,  a_3);
        ((float4*)YL)[c*32 + ((wv*4 + 1) ^ cswz)] = make_float4(a_4,  a_5,  a_6,  a_7);
        ((float4*)YL)[c*32 + ((wv*4 + 2) ^ cswz)] = make_float4(a_8,  a_9,  a_10, a_11);
        ((float4*)YL)[c*32 + ((wv*4 + 3) ^ cswz)] = make_float4(a_12, a_13, a_14, a_15);
    }
    __syncthreads();

    // ---- pass 2: x19 = fe(x18 @ W3.T) -> scatter to out[c][w][h] ----
    {
        bool active = (cb + c) < n_act;
        int cell = active ? act[cb + c] : 0;
        int hh = cell / BEVW;
        int ww = cell - hh * BEVW;
        float* op = out + (size_t)ob*NCELL + ww*BEVH + hh;
        const float4* yrow = (const float4*)YL + c*32;
        REP16_0(DECLB)
        for (int kc = 0; kc < 32; kc++) {
            float4 xv = yrow[kc ^ cswz];
            REP16_0(ACCB)
        }
        REP16_0(ACTB)
        if (active) {
#define STOR(q) op[(q)*NCELL] = a_##q;
            REP16_0(STOR)
#undef STOR
        }
    }
#undef DECLB
#undef ACCB
#undef ACTB
}

extern "C" void kernel_launch(void* const* d_in, const int* in_sizes, int n_in,
                              void* d_out, int out_size, void* d_ws, size_t ws_size,
                              hipStream_t stream) {
    const float* features = (const float*)d_in[0];
    const int*   coors    = (const int*)d_in[1];
    const int*   num_vox  = (const int*)d_in[2];
    const float* vfe1_W   = (const float*)d_in[3];
    const float* vfe1_bn  = (const float*)d_in[4];
    const float* vfe2_W   = (const float*)d_in[5];
    const float* vfe2_bn  = (const float*)d_in[6];
    const float* vfe3_W   = (const float*)d_in[7];
    const float* vfe3_bn  = (const float*)d_in[8];
    const float* vfe4_W   = (const float*)d_in[9];
    const float* vfe4_bn  = (const float*)d_in[10];
    const float* bfe1_W   = (const float*)d_in[11];
    const float* bfe1_bn  = (const float*)d_in[12];
    const float* bfe2_W   = (const float*)d_in[13];
    const float* bfe2_bn  = (const float*)d_in[14];
    const float* bfe3_W   = (const float*)d_in[15];
    const float* bfe3_bn  = (const float*)d_in[16];
    float* out = (float*)d_out;

    char* ws = (char*)d_ws;
    int*   nact      = (int*)ws;
    int*   cnt       = (int*)(ws + 256);
    int*   list      = (int*)(ws + 857600);
    float* voxelwise = (float*)(ws + 14571008);
    int*   act       = (int*)(ws + 24811008);
    float* x17g      = (float*)(ws + 24971008);
    float* fold      = (float*)(ws + 45451008);
    float* w4t       = (float*)(ws + 45455680);

    hipMemsetAsync(ws, 0, 857600, stream);
    hipMemsetAsync(d_out, 0, (size_t)out_size * sizeof(float), stream);

    setup_kernel<<<1, 256, 0, stream>>>(vfe1_bn, vfe2_bn, vfe3_bn, vfe4_bn,
                                        bfe1_bn, bfe2_bn, bfe3_bn, vfe4_W,
                                        fold, w4t);
    vfe_kernel<<<NVOX/4, 128, 0, stream>>>(features, coors, num_vox,
                                           vfe1_W, vfe2_W, vfe3_W, w4t, fold,
                                           voxelwise, cnt, list, nact, act);
    bfe_front<<<NVOX/4, 256, 0, stream>>>(nact, act, cnt, list, voxelwise,
                                          bfe1_W, bfe2_W, fold, x17g);
    bfe3_fused<<<(NVOX+63)/64, 512, 0, stream>>>(nact, act, bfe3_W, fold, x17g, out);
}

// Round 7
// 698.800 us; speedup vs baseline: 2.1777x; 1.2502x over previous
//
#include <hip/hip_runtime.h>

#define BEVW 432
#define BEVH 496
#define NCELL (BEVW*BEVH)      // 214272
#define NVOX  40000
#define EPSB  1e-5f

// ---- repeat macros (token-pasted literal indices) ----
#define REP8_0(M)  M(0) M(1) M(2) M(3) M(4) M(5) M(6) M(7)
#define REP8_8(M)  M(8) M(9) M(10) M(11) M(12) M(13) M(14) M(15)
#define REP8_16(M) M(16) M(17) M(18) M(19) M(20) M(21) M(22) M(23)
#define REP8_24(M) M(24) M(25) M(26) M(27) M(28) M(29) M(30) M(31)
#define REP8_32(M) M(32) M(33) M(34) M(35) M(36) M(37) M(38) M(39)
#define REP8_40(M) M(40) M(41) M(42) M(43) M(44) M(45) M(46) M(47)
#define REP8_48(M) M(48) M(49) M(50) M(51) M(52) M(53) M(54) M(55)
#define REP8_56(M) M(56) M(57) M(58) M(59) M(60) M(61) M(62) M(63)
#define REP16_0(M)  REP8_0(M)  REP8_8(M)
#define REP16_16(M) REP8_16(M) REP8_24(M)
#define REP16_32(M) REP8_32(M) REP8_40(M)
#define REP16_48(M) REP8_48(M) REP8_56(M)
#define REP32_0(M) REP16_0(M) REP16_16(M)
#define REP64_0(M) REP32_0(M) REP16_32(M) REP16_48(M)

// ---------------- workspace layout (bytes) ----------------
// 0        : int nact (zeroed) | 256: int cnt[NCELL] (zeroed)
// 857600   : int list[NCELL*16]
// 14571008 : float voxelwise[NVOX*64]
// 24811008 : int act[NVOX]
// 24971008 : float x17g[NVOX*128]
// 45451008 : float fold[1168]
// 45455680 : float w4t[4096]

__device__ __forceinline__ float mishf(float y) {
    float e = __expf(fminf(y, 40.f));
    float n = e * (e + 2.f);
    return y * n * __builtin_amdgcn_rcpf(n + 2.f);
}

// DPP-based 32-lane max reduce: stages 1,2,4,8 as VALU DPP (quad_perm/mirrors
// are involutions pairing the halves -> valid for max), xor16 via ds_swizzle.
// ctrl must be a constant-expression -> template parameter.
template <int CTRL>
__device__ __forceinline__ float dppmaxf(float a) {
    int p = __builtin_amdgcn_update_dpp(0, __float_as_int(a), CTRL, 0xF, 0xF, true);
    return fmaxf(a, __int_as_float(p));
}
#define WMAX32(a) { \
    a = dppmaxf<0xB1>(a);   /* quad_perm [1,0,3,2]  : xor1 */ \
    a = dppmaxf<0x4E>(a);   /* quad_perm [2,3,0,1]  : xor2 */ \
    a = dppmaxf<0x141>(a);  /* row_half_mirror      : pairs 0-3<->4-7 */ \
    a = dppmaxf<0x140>(a);  /* row_mirror           : pairs 0-7<->8-15 */ \
    a = fmaxf(a, __int_as_float(__builtin_amdgcn_ds_swizzle(__float_as_int(a), 0x401F))); /* xor16 */ }

__device__ __forceinline__ float finpool(float acc, float base, float s, float tf, float maskf) {
    float y = acc * s + tf;
    y = mishf(y) * maskf + base;
    WMAX32(y);
    return y;
}

// fold layout: vfe1 s@0 t@8 | vfe2 s@16 t@48 | vfe3 s@80 t@144 | vfe4 s@208 t@272
// bfe3 s@336 t@464 | bfe1 s@592 t@848 | bfe2 s@1104 t@1136
__global__ __launch_bounds__(256) void setup_kernel(
    const float* __restrict__ vbn1, const float* __restrict__ vbn2,
    const float* __restrict__ vbn3, const float* __restrict__ vbn4,
    const float* __restrict__ bbn1, const float* __restrict__ bbn2,
    const float* __restrict__ bbn3, const float* __restrict__ W4,
    float* __restrict__ fold, float* __restrict__ w4t)
{
    int tid = threadIdx.x;
    if (tid < 8)  { float s = vbn1[tid]/sqrtf(vbn1[24+tid]+EPSB);  fold[tid]      = s; fold[8+tid]   = vbn1[8+tid]  - vbn1[16+tid]*s; }
    if (tid < 32) { float s = vbn2[tid]/sqrtf(vbn2[96+tid]+EPSB);  fold[16+tid]   = s; fold[48+tid]  = vbn2[32+tid] - vbn2[64+tid]*s; }
    if (tid < 64) { float s = vbn3[tid]/sqrtf(vbn3[192+tid]+EPSB); fold[80+tid]   = s; fold[144+tid] = vbn3[64+tid] - vbn3[128+tid]*s; }
    if (tid < 64) { float s = vbn4[tid]/sqrtf(vbn4[192+tid]+EPSB); fold[208+tid]  = s; fold[272+tid] = vbn4[64+tid] - vbn4[128+tid]*s; }
    if (tid < 128){ float s = bbn3[tid]/sqrtf(bbn3[384+tid]+EPSB); fold[336+tid]  = s; fold[464+tid] = bbn3[128+tid]- bbn3[256+tid]*s; }
    { int g = tid >> 4, q = tid & 15;
      const float* b = bbn1 + g*64;
      float s = b[q]/sqrtf(b[48+q]+EPSB);
      fold[592+tid] = s; fold[848+tid] = b[16+q] - b[32+q]*s; }
    if (tid < 32) { int g = tid >> 1, c = tid & 1;
      const float* b = bbn2 + g*8;
      float s = b[c]/sqrtf(b[6+c]+EPSB);
      fold[1104+tid] = s; fold[1136+tid] = b[2+c] - b[4+c]*s; }
    for (int i = tid; i < 4096; i += 256) { int o = i >> 6, c = i & 63; w4t[c*64+o] = W4[i]; }
}

// ---------------- VFE: 8 voxels / 256-thr block, lane=point (round-4 structure) ----
__global__ __launch_bounds__(256, 2) void vfe_kernel(
    const float* __restrict__ feat, const int* __restrict__ coors,
    const int* __restrict__ nvx,
    const float* __restrict__ W1, const float* __restrict__ W2,
    const float* __restrict__ W3, const float* __restrict__ W4T,
    const float* __restrict__ fold,
    float* __restrict__ voxelwise, int* __restrict__ cnt,
    int* __restrict__ list, int* __restrict__ nact, int* __restrict__ act)
{
    int tid = threadIdx.x;
    int v = blockIdx.x * 8 + (tid >> 5);
    int t = tid & 31;

    const float* fp = feat + (v*32 + t)*8;
    float4 fa = *(const float4*)fp;
    float4 fb = *(const float4*)(fp+4);
    int numv = nvx[v];
    float maskf = (t < numv) ? 1.f : 0.f;

    // ---- fe1 (8->8) + pool ----
#define D1(o) float x1_##o; float m1_##o;
    REP8_0(D1)
#undef D1
#define FE1(o) { const float* w = W1 + (o)*8; \
    float ya = fa.x*w[0] + fa.y*w[1]; float yb = fa.z*w[2] + fa.w*w[3]; \
    float yc = fb.x*w[4] + fb.y*w[5]; float yd = fb.z*w[6] + fb.w*w[7]; \
    float yy = ((ya+yb)+(yc+yd)) * fold[(o)] + fold[8+(o)]; \
    x1_##o = mishf(yy); }
    REP8_0(FE1)
#undef FE1
#define P1(o) { float a = x1_##o; WMAX32(a); m1_##o = a; }
    REP8_0(P1)
#undef P1

    // ---- fe2 (16->32) + pool ----
#define D2(o) float x2_##o; float agg_##o;
    REP32_0(D2)
#undef D2
#define FE2(o) { const float* w = W2 + (o)*16; \
    float ya = x1_0*w[0]+x1_1*w[1]+x1_2*w[2]+x1_3*w[3]; \
    float yb = x1_4*w[4]+x1_5*w[5]+x1_6*w[6]+x1_7*w[7]; \
    float yc = m1_0*w[8]+m1_1*w[9]+m1_2*w[10]+m1_3*w[11]; \
    float yd = m1_4*w[12]+m1_5*w[13]+m1_6*w[14]+m1_7*w[15]; \
    float yy = ((ya+yb)+(yc+yd)) * fold[16+(o)] + fold[48+(o)]; \
    x2_##o = mishf(yy); }
    REP32_0(FE2)
#undef FE2
#define P2(o) { float a = x2_##o; WMAX32(a); agg_##o = a; }
    REP32_0(P2)
#undef P2

    // ---- yagg: fe3 contribution of the voxel-uniform aggregate half ----
    const float* wa = W3 + t*64 + 32;
    const float* wb = W3 + (t+32)*64 + 32;
    float yagg1 = 0.f, yagg2 = 0.f;
#define YG(j) yagg1 += agg_##j * wa[j]; yagg2 += agg_##j * wb[j];
    REP32_0(YG)
#undef YG

#define MSK(o) x2_##o *= maskf; agg_##o *= maskf;
    REP32_0(MSK)
#undef MSK

    // ---- fe3 (64->64) + incremental fe4 ----
#define ACD(q) float acc_##q = 0.f;
    REP64_0(ACD)
#undef ACD
    for (int o = 0; o < 64; o++) {
        const float* w3r = W3 + o*64;
        float s0=0.f, s1=0.f, s2=0.f, s3=0.f;
#define F3A(c) s0 += x2_##c * w3r[c];
#define F3B(c) s1 += x2_##c * w3r[c];
#define F3C(c) s2 += x2_##c * w3r[c];
#define F3D(c) s3 += x2_##c * w3r[c];
        REP8_0(F3A) REP8_8(F3B) REP8_16(F3C) REP8_24(F3D)
#undef F3A
#undef F3B
#undef F3C
#undef F3D
        float ysrc = (o < 32) ? yagg1 : yagg2;
        float ya = __shfl(ysrc, (o & 31), 32);
        float yy = ((s0+s1)+(s2+s3)) + maskf * ya;
        yy = yy * fold[80+o] + fold[144+o];
        float x3 = mishf(yy);
        const float* w4r = W4T + o*64;
#define F4(q) acc_##q += x3 * w4r[q];
        REP64_0(F4)
#undef F4
    }

    // ---- bn4 + mish + residual + pool, store per quad ----
#define FQ(q0,q1,q2,q3,b0,b1,b2,b3) { \
    float r0 = finpool(acc_##q0, b0, fold[208+q0], fold[272+q0], maskf); \
    float r1 = finpool(acc_##q1, b1, fold[208+q1], fold[272+q1], maskf); \
    float r2 = finpool(acc_##q2, b2, fold[208+q2], fold[272+q2], maskf); \
    float r3 = finpool(acc_##q3, b3, fold[208+q3], fold[272+q3], maskf); \
    if (t == 0) *(float4*)(voxelwise + v*64 + q0) = make_float4(r0,r1,r2,r3); }
    FQ(0,1,2,3,     x2_0,x2_1,x2_2,x2_3)
    FQ(4,5,6,7,     x2_4,x2_5,x2_6,x2_7)
    FQ(8,9,10,11,   x2_8,x2_9,x2_10,x2_11)
    FQ(12,13,14,15, x2_12,x2_13,x2_14,x2_15)
    FQ(16,17,18,19, x2_16,x2_17,x2_18,x2_19)
    FQ(20,21,22,23, x2_20,x2_21,x2_22,x2_23)
    FQ(24,25,26,27, x2_24,x2_25,x2_26,x2_27)
    FQ(28,29,30,31, x2_28,x2_29,x2_30,x2_31)
    FQ(32,33,34,35, agg_0,agg_1,agg_2,agg_3)
    FQ(36,37,38,39, agg_4,agg_5,agg_6,agg_7)
    FQ(40,41,42,43, agg_8,agg_9,agg_10,agg_11)
    FQ(44,45,46,47, agg_12,agg_13,agg_14,agg_15)
    FQ(48,49,50,51, agg_16,agg_17,agg_18,agg_19)
    FQ(52,53,54,55, agg_20,agg_21,agg_22,agg_23)
    FQ(56,57,58,59, agg_24,agg_25,agg_26,agg_27)
    FQ(60,61,62,63, agg_28,agg_29,agg_30,agg_31)
#undef FQ

    if (t == 0) {
        int cell = coors[v*2] * BEVW + coors[v*2+1];
        int pos = atomicAdd(&cnt[cell], 1);
        if (pos < 16) list[cell*16 + pos] = v;
        if (pos == 0) { int k = atomicAdd(nact, 1); act[k] = cell; }
    }
}

// ---------------- BFE front: 1 wave = 1 cell; weights direct from L1 ----------------
__global__ __launch_bounds__(256) void bfe_front(
    const int* __restrict__ nact, const int* __restrict__ act,
    const int* __restrict__ cnt, const int* __restrict__ list,
    const float* __restrict__ voxelwise,
    const float* __restrict__ W1g, const float* __restrict__ W2g,
    const float* __restrict__ fold, float* __restrict__ x17g)
{
    int n_act = *nact;
    int aidx = blockIdx.x * 4 + (threadIdx.x >> 6);
    if (aidx >= n_act) return;

    int lane = threadIdx.x & 63;
    int g = lane >> 2, ii = lane & 3;
    int cell = act[aidx];
    int numv = min(cnt[cell], 16);

    int myidx = (lane < numv) ? list[cell*16 + lane] : (0x40000000 + lane);
    int rank = 0;
    for (int j = 0; j < numv; j++) { int vj = __shfl(myidx, j); rank += (vj < myidx) ? 1 : 0; }
    if (lane >= numv) rank = lane;
    int sorted = __builtin_amdgcn_ds_permute(rank << 2, myidx);

#define YD(q) float y_##q = 0.f;
    REP16_0(YD)
#undef YD
    for (int p = 0; p < numv; p++) {
        int sv = __shfl(sorted, p);
        float val = voxelwise[sv*64 + lane];
        const float* w = W1g + g*256 + p;
#define BF1(q) y_##q += val * w[(q)*16];
        REP16_0(BF1)
#undef BF1
    }
#define BN1(q) { float yy = y_##q * fold[592 + g*16 + (q)] + fold[848 + g*16 + (q)]; \
    yy = mishf(yy); y_##q = ((q) < numv) ? yy : 0.f; }
    REP16_0(BN1)
#undef BN1

    float z0 = 0.f, z1 = 0.f;
#define BF2(p) z0 += y_##p * W2g[g*32 + (p)]; z1 += y_##p * W2g[g*32 + 16 + (p)];
    REP16_0(BF2)
#undef BF2
    z0 = mishf(z0 * fold[1104 + g*2 + 0] + fold[1136 + g*2 + 0]);
    z1 = mishf(z1 * fold[1104 + g*2 + 1] + fold[1136 + g*2 + 1]);

    int k0 = ii*32 + g*2;
    *(float2*)(x17g + aidx*128 + k0) = make_float2(z0, z1);
}

// ---------------- bfe3 fused (x18 and x19): GEMM-shaped ----------------
__global__ __launch_bounds__(512, 1) void bfe3_fused(
    const int* __restrict__ nactp, const int* __restrict__ act,
    const float* __restrict__ W3, const float* __restrict__ fold,
    const float* __restrict__ x17g, float* __restrict__ out)
{
    __shared__ float XL[64*128];   // float4-chunk XOR swizzle: chunk kc at kc^(c&31)
    __shared__ float YL[64*128];
    int tid = threadIdx.x;
    int n_act = *nactp;
    int cb = blockIdx.x * 64;

    for (int i = tid; i < 64*32; i += 512) {
        int c = i >> 5, kc = i & 31;
        float4 val = (cb + c < n_act) ? ((const float4*)x17g)[(size_t)(cb+c)*32 + kc]
                                      : make_float4(0.f,0.f,0.f,0.f);
        ((float4*)XL)[c*32 + (kc ^ (c & 31))] = val;
    }
    __syncthreads();

    int wv = __builtin_amdgcn_readfirstlane(tid >> 6);
    int c  = tid & 63;
    int ob = wv * 16;
    int cswz = c & 31;
    const float4* xrow = (const float4*)XL + c*32;
    const float4* W4p = (const float4*)W3;

#define DECLB(q) float a_##q = 0.f;
#define ACCB(q) { float4 wq = W4p[(ob+(q))*32 + kc]; \
    a_##q += xv.x*wq.x + xv.y*wq.y + xv.z*wq.z + xv.w*wq.w; }
#define ACTB(q) { float yy = a_##q * fold[336+ob+(q)] + fold[464+ob+(q)]; a_##q = mishf(yy); }
    {
        REP16_0(DECLB)
        for (int kc = 0; kc < 32; kc++) {
            float4 xv = xrow[kc ^ cswz];
            REP16_0(ACCB)
        }
        REP16_0(ACTB)
        ((float4*)YL)[c*32 + ((wv*4 + 0) ^ cswz)] = make_float4(a_0,  a_1,  a_2,  a_3);
        ((float4*)YL)[c*32 + ((wv*4 + 1) ^ cswz)] = make_float4(a_4,  a_5,  a_6,  a_7);
        ((float4*)YL)[c*32 + ((wv*4 + 2) ^ cswz)] = make_float4(a_8,  a_9,  a_10, a_11);
        ((float4*)YL)[c*32 + ((wv*4 + 3) ^ cswz)] = make_float4(a_12, a_13, a_14, a_15);
    }
    __syncthreads();

    {
        bool active = (cb + c) < n_act;
        int cell = active ? act[cb + c] : 0;
        int hh = cell / BEVW;
        int ww = cell - hh * BEVW;
        float* op = out + (size_t)ob*NCELL + ww*BEVH + hh;
        const float4* yrow = (const float4*)YL + c*32;
        REP16_0(DECLB)
        for (int kc = 0; kc < 32; kc++) {
            float4 xv = yrow[kc ^ cswz];
            REP16_0(ACCB)
        }
        REP16_0(ACTB)
        if (active) {
#define STOR(q) op[(q)*NCELL] = a_##q;
            REP16_0(STOR)
#undef STOR
        }
    }
#undef DECLB
#undef ACCB
#undef ACTB
}

extern "C" void kernel_launch(void* const* d_in, const int* in_sizes, int n_in,
                              void* d_out, int out_size, void* d_ws, size_t ws_size,
                              hipStream_t stream) {
    const float* features = (const float*)d_in[0];
    const int*   coors    = (const int*)d_in[1];
    const int*   num_vox  = (const int*)d_in[2];
    const float* vfe1_W   = (const float*)d_in[3];
    const float* vfe1_bn  = (const float*)d_in[4];
    const float* vfe2_W   = (const float*)d_in[5];
    const float* vfe2_bn  = (const float*)d_in[6];
    const float* vfe3_W   = (const float*)d_in[7];
    const float* vfe3_bn  = (const float*)d_in[8];
    const float* vfe4_W   = (const float*)d_in[9];
    const float* vfe4_bn  = (const float*)d_in[10];
    const float* bfe1_W   = (const float*)d_in[11];
    const float* bfe1_bn  = (const float*)d_in[12];
    const float* bfe2_W   = (const float*)d_in[13];
    const float* bfe2_bn  = (const float*)d_in[14];
    const float* bfe3_W   = (const float*)d_in[15];
    const float* bfe3_bn  = (const float*)d_in[16];
    float* out = (float*)d_out;

    char* ws = (char*)d_ws;
    int*   nact      = (int*)ws;
    int*   cnt       = (int*)(ws + 256);
    int*   list      = (int*)(ws + 857600);
    float* voxelwise = (float*)(ws + 14571008);
    int*   act       = (int*)(ws + 24811008);
    float* x17g      = (float*)(ws + 24971008);
    float* fold      = (float*)(ws + 45451008);
    float* w4t       = (float*)(ws + 45455680);

    (void)hipMemsetAsync(ws, 0, 857600, stream);
    (void)hipMemsetAsync(d_out, 0, (size_t)out_size * sizeof(float), stream);

    setup_kernel<<<1, 256, 0, stream>>>(vfe1_bn, vfe2_bn, vfe3_bn, vfe4_bn,
                                        bfe1_bn, bfe2_bn, bfe3_bn, vfe4_W,
                                        fold, w4t);
    vfe_kernel<<<NVOX/8, 256, 0, stream>>>(features, coors, num_vox,
                                           vfe1_W, vfe2_W, vfe3_W, w4t, fold,
                                           voxelwise, cnt, list, nact, act);
    bfe_front<<<NVOX/4, 256, 0, stream>>>(nact, act, cnt, list, voxelwise,
                                          bfe1_W, bfe2_W, fold, x17g);
    bfe3_fused<<<(NVOX+63)/64, 512, 0, stream>>>(nact, act, bfe3_W, fold, x17g, out);
}

// Round 8
// 681.405 us; speedup vs baseline: 2.2333x; 1.0255x over previous
//
#include <hip/hip_runtime.h>

#define BEVW 432
#define BEVH 496
#define NCELL (BEVW*BEVH)      // 214272
#define NVOX  40000
#define EPSB  1e-5f

typedef float f32x2 __attribute__((ext_vector_type(2)));

// ---- repeat macros (token-pasted literal indices) ----
#define REP8_0(M)  M(0) M(1) M(2) M(3) M(4) M(5) M(6) M(7)
#define REP8_8(M)  M(8) M(9) M(10) M(11) M(12) M(13) M(14) M(15)
#define REP8_16(M) M(16) M(17) M(18) M(19) M(20) M(21) M(22) M(23)
#define REP8_24(M) M(24) M(25) M(26) M(27) M(28) M(29) M(30) M(31)
#define REP16_0(M)  REP8_0(M)  REP8_8(M)
#define REP32_0(M) REP16_0(M) REP8_16(M) REP8_24(M)

// ---------------- workspace layout (bytes) ----------------
// 0        : int nact (zeroed) | 256: int cnt[NCELL] (zeroed)
// 857600   : int list[NCELL*16]
// 14571008 : float voxelwise[NVOX*64]
// 24811008 : int act[NVOX]
// 24971008 : float x17g[NVOX*128]
// 45451008 : float fold[1168]
// 45455680 : float w4t[4096]

__device__ __forceinline__ float mishf(float y) {
    float e = __expf(fminf(y, 40.f));
    float n = e * (e + 2.f);
    return y * n * __builtin_amdgcn_rcpf(n + 2.f);
}

// DPP-based 32-lane max reduce (round-7, kept: neutral vs shfl but fewer LDS ops)
template <int CTRL>
__device__ __forceinline__ float dppmaxf(float a) {
    int p = __builtin_amdgcn_update_dpp(0, __float_as_int(a), CTRL, 0xF, 0xF, true);
    return fmaxf(a, __int_as_float(p));
}
#define WMAX32(a) { \
    a = dppmaxf<0xB1>(a); \
    a = dppmaxf<0x4E>(a); \
    a = dppmaxf<0x141>(a); \
    a = dppmaxf<0x140>(a); \
    a = fmaxf(a, __int_as_float(__builtin_amdgcn_ds_swizzle(__float_as_int(a), 0x401F))); }

__device__ __forceinline__ float finpool(float acc, float base, float s, float tf, float maskf) {
    float y = acc * s + tf;
    y = mishf(y) * maskf + base;
    WMAX32(y);
    return y;
}

// fold layout: vfe1 s@0 t@8 | vfe2 s@16 t@48 | vfe3 s@80 t@144 | vfe4 s@208 t@272
// bfe3 s@336 t@464 | bfe1 s@592 t@848 | bfe2 s@1104 t@1136
__global__ __launch_bounds__(256) void setup_kernel(
    const float* __restrict__ vbn1, const float* __restrict__ vbn2,
    const float* __restrict__ vbn3, const float* __restrict__ vbn4,
    const float* __restrict__ bbn1, const float* __restrict__ bbn2,
    const float* __restrict__ bbn3, const float* __restrict__ W4,
    float* __restrict__ fold, float* __restrict__ w4t)
{
    int tid = threadIdx.x;
    if (tid < 8)  { float s = vbn1[tid]/sqrtf(vbn1[24+tid]+EPSB);  fold[tid]      = s; fold[8+tid]   = vbn1[8+tid]  - vbn1[16+tid]*s; }
    if (tid < 32) { float s = vbn2[tid]/sqrtf(vbn2[96+tid]+EPSB);  fold[16+tid]   = s; fold[48+tid]  = vbn2[32+tid] - vbn2[64+tid]*s; }
    if (tid < 64) { float s = vbn3[tid]/sqrtf(vbn3[192+tid]+EPSB); fold[80+tid]   = s; fold[144+tid] = vbn3[64+tid] - vbn3[128+tid]*s; }
    if (tid < 64) { float s = vbn4[tid]/sqrtf(vbn4[192+tid]+EPSB); fold[208+tid]  = s; fold[272+tid] = vbn4[64+tid] - vbn4[128+tid]*s; }
    if (tid < 128){ float s = bbn3[tid]/sqrtf(bbn3[384+tid]+EPSB); fold[336+tid]  = s; fold[464+tid] = bbn3[128+tid]- bbn3[256+tid]*s; }
    { int g = tid >> 4, q = tid & 15;
      const float* b = bbn1 + g*64;
      float s = b[q]/sqrtf(b[48+q]+EPSB);
      fold[592+tid] = s; fold[848+tid] = b[16+q] - b[32+q]*s; }
    if (tid < 32) { int g = tid >> 1, c = tid & 1;
      const float* b = bbn2 + g*8;
      float s = b[c]/sqrtf(b[6+c]+EPSB);
      fold[1104+tid] = s; fold[1136+tid] = b[2+c] - b[4+c]*s; }
    for (int i = tid; i < 4096; i += 256) { int o = i >> 6, c = i & 63; w4t[c*64+o] = W4[i]; }
}

// pair list: (pair index, scalar a, scalar b)
#define PAIRS(M) M(0,0,1) M(1,2,3) M(2,4,5) M(3,6,7) M(4,8,9) M(5,10,11) \
  M(6,12,13) M(7,14,15) M(8,16,17) M(9,18,19) M(10,20,21) M(11,22,23) \
  M(12,24,25) M(13,26,27) M(14,28,29) M(15,30,31)

// ---------------- VFE: 8 voxels / 256-thr block, lane=point ----------------
// All hot dots as f32x2 ops -> v_pk_fma_f32 (2 FLOP/lane/instr; the only path
// to the 157 TF fp32 peak). Weights via wave-uniform rows stay in SGPRs.
__global__ __launch_bounds__(256, 2) void vfe_kernel(
    const float* __restrict__ feat, const int* __restrict__ coors,
    const int* __restrict__ nvx,
    const float* __restrict__ W1, const float* __restrict__ W2,
    const float* __restrict__ W3, const float* __restrict__ W4T,
    const float* __restrict__ fold,
    float* __restrict__ voxelwise, int* __restrict__ cnt,
    int* __restrict__ list, int* __restrict__ nact, int* __restrict__ act)
{
    int tid = threadIdx.x;
    int v = blockIdx.x * 8 + (tid >> 5);
    int t = tid & 31;

    const float* fp = feat + (v*32 + t)*8;
    float4 fa = *(const float4*)fp;
    float4 fb = *(const float4*)(fp+4);
    int numv = nvx[v];
    float maskf = (t < numv) ? 1.f : 0.f;

    // ---- fe1 (8->8) + pool ----
#define D1(o) float x1_##o; float m1_##o;
    REP8_0(D1)
#undef D1
#define FE1(o) { const float* w = W1 + (o)*8; \
    float ya = fa.x*w[0] + fa.y*w[1]; float yb = fa.z*w[2] + fa.w*w[3]; \
    float yc = fb.x*w[4] + fb.y*w[5]; float yd = fb.z*w[6] + fb.w*w[7]; \
    float yy = ((ya+yb)+(yc+yd)) * fold[(o)] + fold[8+(o)]; \
    x1_##o = mishf(yy); }
    REP8_0(FE1)
#undef FE1
#define P1(o) { float a = x1_##o; WMAX32(a); m1_##o = a; }
    REP8_0(P1)
#undef P1

    // pack x1/m1 into pairs for fe2
    f32x2 x1p_0 = {x1_0,x1_1}, x1p_1 = {x1_2,x1_3}, x1p_2 = {x1_4,x1_5}, x1p_3 = {x1_6,x1_7};
    f32x2 m1p_0 = {m1_0,m1_1}, m1p_1 = {m1_2,m1_3}, m1p_2 = {m1_4,m1_5}, m1p_3 = {m1_6,m1_7};

    // ---- fe2 (16->32) + pool, packed dots ----
#define D2(o) float x2_##o; float agg_##o;
    REP32_0(D2)
#undef D2
#define FE2(o) { const f32x2* wp = (const f32x2*)(W2 + (o)*16); \
    f32x2 sa = x1p_0*wp[0]; sa += x1p_1*wp[1]; \
    f32x2 sb = x1p_2*wp[2]; sb += x1p_3*wp[3]; \
    f32x2 sc = m1p_0*wp[4]; sc += m1p_1*wp[5]; \
    f32x2 sd = m1p_2*wp[6]; sd += m1p_3*wp[7]; \
    sa += sb; sc += sd; sa += sc; \
    float yy = (sa.x + sa.y) * fold[16+(o)] + fold[48+(o)]; \
    x2_##o = mishf(yy); }
    REP32_0(FE2)
#undef FE2
#define P2(o) { float a = x2_##o; WMAX32(a); agg_##o = a; }
    REP32_0(P2)
#undef P2

    // pack x2/agg pairs (unmasked; yagg uses unmasked agg per reference)
#define PX(i,a,b) f32x2 x2p_##i = {x2_##a, x2_##b}; f32x2 aggp_##i = {agg_##a, agg_##b};
    PAIRS(PX)
#undef PX

    // ---- yagg: fe3 contribution of the voxel-uniform aggregate half ----
    const f32x2* wap = (const f32x2*)(W3 + t*64 + 32);
    const f32x2* wbp = (const f32x2*)(W3 + (t+32)*64 + 32);
    f32x2 yp1 = {0.f,0.f}, yp2 = {0.f,0.f};
#define YG(i) yp1 += aggp_##i * wap[i]; yp2 += aggp_##i * wbp[i];
    REP16_0(YG)
#undef YG
    float yagg1 = yp1.x + yp1.y, yagg2 = yp2.x + yp2.y;

    // ---- mask pairs ----
    f32x2 maskp = {maskf, maskf};
#define MSK(i) x2p_##i *= maskp; aggp_##i *= maskp;
    REP16_0(MSK)
#undef MSK

    // ---- fe3 (64->64) + incremental fe4, packed ----
#define ACD(q) f32x2 accp_##q = {0.f, 0.f};
    REP32_0(ACD)
#undef ACD
    for (int o = 0; o < 64; o++) {
        const f32x2* wp = (const f32x2*)(W3 + o*64);
        f32x2 s0 = x2p_0*wp[0];  s0 += x2p_1*wp[1];  s0 += x2p_2*wp[2];  s0 += x2p_3*wp[3];
        f32x2 s1 = x2p_4*wp[4];  s1 += x2p_5*wp[5];  s1 += x2p_6*wp[6];  s1 += x2p_7*wp[7];
        f32x2 s2 = x2p_8*wp[8];  s2 += x2p_9*wp[9];  s2 += x2p_10*wp[10]; s2 += x2p_11*wp[11];
        f32x2 s3 = x2p_12*wp[12]; s3 += x2p_13*wp[13]; s3 += x2p_14*wp[14]; s3 += x2p_15*wp[15];
        s0 += s1; s2 += s3; s0 += s2;
        float dot = s0.x + s0.y;
        float ysrc = (o < 32) ? yagg1 : yagg2;
        float ya = __shfl(ysrc, (o & 31), 32);
        float yy = dot + maskf * ya;
        yy = yy * fold[80+o] + fold[144+o];
        float x3 = mishf(yy);
        f32x2 x3p = {x3, x3};
        const f32x2* w4p = (const f32x2*)(W4T + o*64);
#define F4(q) accp_##q += x3p * w4p[q];
        REP32_0(F4)
#undef F4
    }

    // ---- bn4 + mish + residual + pool, store per quad ----
#define FQ4(q0, A0,B0, A1,B1, A2,B2, A3,B3) { \
    float r0 = finpool(A0, B0, fold[208+q0],   fold[272+q0],   maskf); \
    float r1 = finpool(A1, B1, fold[208+q0+1], fold[272+q0+1], maskf); \
    float r2 = finpool(A2, B2, fold[208+q0+2], fold[272+q0+2], maskf); \
    float r3 = finpool(A3, B3, fold[208+q0+3], fold[272+q0+3], maskf); \
    if (t == 0) *(float4*)(voxelwise + v*64 + q0) = make_float4(r0,r1,r2,r3); }
    FQ4(0,  accp_0.x,x2p_0.x,  accp_0.y,x2p_0.y,  accp_1.x,x2p_1.x,  accp_1.y,x2p_1.y)
    FQ4(4,  accp_2.x,x2p_2.x,  accp_2.y,x2p_2.y,  accp_3.x,x2p_3.x,  accp_3.y,x2p_3.y)
    FQ4(8,  accp_4.x,x2p_4.x,  accp_4.y,x2p_4.y,  accp_5.x,x2p_5.x,  accp_5.y,x2p_5.y)
    FQ4(12, accp_6.x,x2p_6.x,  accp_6.y,x2p_6.y,  accp_7.x,x2p_7.x,  accp_7.y,x2p_7.y)
    FQ4(16, accp_8.x,x2p_8.x,  accp_8.y,x2p_8.y,  accp_9.x,x2p_9.x,  accp_9.y,x2p_9.y)
    FQ4(20, accp_10.x,x2p_10.x, accp_10.y,x2p_10.y, accp_11.x,x2p_11.x, accp_11.y,x2p_11.y)
    FQ4(24, accp_12.x,x2p_12.x, accp_12.y,x2p_12.y, accp_13.x,x2p_13.x, accp_13.y,x2p_13.y)
    FQ4(28, accp_14.x,x2p_14.x, accp_14.y,x2p_14.y, accp_15.x,x2p_15.x, accp_15.y,x2p_15.y)
    FQ4(32, accp_16.x,aggp_0.x, accp_16.y,aggp_0.y, accp_17.x,aggp_1.x, accp_17.y,aggp_1.y)
    FQ4(36, accp_18.x,aggp_2.x, accp_18.y,aggp_2.y, accp_19.x,aggp_3.x, accp_19.y,aggp_3.y)
    FQ4(40, accp_20.x,aggp_4.x, accp_20.y,aggp_4.y, accp_21.x,aggp_5.x, accp_21.y,aggp_5.y)
    FQ4(44, accp_22.x,aggp_6.x, accp_22.y,aggp_6.y, accp_23.x,aggp_7.x, accp_23.y,aggp_7.y)
    FQ4(48, accp_24.x,aggp_8.x, accp_24.y,aggp_8.y, accp_25.x,aggp_9.x, accp_25.y,aggp_9.y)
    FQ4(52, accp_26.x,aggp_10.x, accp_26.y,aggp_10.y, accp_27.x,aggp_11.x, accp_27.y,aggp_11.y)
    FQ4(56, accp_28.x,aggp_12.x, accp_28.y,aggp_12.y, accp_29.x,aggp_13.x, accp_29.y,aggp_13.y)
    FQ4(60, accp_30.x,aggp_14.x, accp_30.y,aggp_14.y, accp_31.x,aggp_15.x, accp_31.y,aggp_15.y)
#undef FQ4

    if (t == 0) {
        int cell = coors[v*2] * BEVW + coors[v*2+1];
        int pos = atomicAdd(&cnt[cell], 1);
        if (pos < 16) list[cell*16 + pos] = v;
        if (pos == 0) { int k = atomicAdd(nact, 1); act[k] = cell; }
    }
}

// ---------------- BFE front: 1 wave = 1 cell; weights direct from L1 ----------------
__global__ __launch_bounds__(256) void bfe_front(
    const int* __restrict__ nact, const int* __restrict__ act,
    const int* __restrict__ cnt, const int* __restrict__ list,
    const float* __restrict__ voxelwise,
    const float* __restrict__ W1g, const float* __restrict__ W2g,
    const float* __restrict__ fold, float* __restrict__ x17g)
{
    int n_act = *nact;
    int aidx = blockIdx.x * 4 + (threadIdx.x >> 6);
    if (aidx >= n_act) return;

    int lane = threadIdx.x & 63;
    int g = lane >> 2, ii = lane & 3;
    int cell = act[aidx];
    int numv = min(cnt[cell], 16);

    int myidx = (lane < numv) ? list[cell*16 + lane] : (0x40000000 + lane);
    int rank = 0;
    for (int j = 0; j < numv; j++) { int vj = __shfl(myidx, j); rank += (vj < myidx) ? 1 : 0; }
    if (lane >= numv) rank = lane;
    int sorted = __builtin_amdgcn_ds_permute(rank << 2, myidx);

#define YD(q) float y_##q = 0.f;
    REP16_0(YD)
#undef YD
    for (int p = 0; p < numv; p++) {
        int sv = __shfl(sorted, p);
        float val = voxelwise[sv*64 + lane];
        const float* w = W1g + g*256 + p;
#define BF1(q) y_##q += val * w[(q)*16];
        REP16_0(BF1)
#undef BF1
    }
#define BN1(q) { float yy = y_##q * fold[592 + g*16 + (q)] + fold[848 + g*16 + (q)]; \
    yy = mishf(yy); y_##q = ((q) < numv) ? yy : 0.f; }
    REP16_0(BN1)
#undef BN1

    float z0 = 0.f, z1 = 0.f;
#define BF2(p) z0 += y_##p * W2g[g*32 + (p)]; z1 += y_##p * W2g[g*32 + 16 + (p)];
    REP16_0(BF2)
#undef BF2
    z0 = mishf(z0 * fold[1104 + g*2 + 0] + fold[1136 + g*2 + 0]);
    z1 = mishf(z1 * fold[1104 + g*2 + 1] + fold[1136 + g*2 + 1]);

    int k0 = ii*32 + g*2;
    *(float2*)(x17g + aidx*128 + k0) = make_float2(z0, z1);
}

// ---------------- bfe3 fused (x18 and x19): GEMM-shaped, packed f32 ----------------
__global__ __launch_bounds__(512, 1) void bfe3_fused(
    const int* __restrict__ nactp, const int* __restrict__ act,
    const float* __restrict__ W3, const float* __restrict__ fold,
    const float* __restrict__ x17g, float* __restrict__ out)
{
    __shared__ float XL[64*128];   // float4-chunk XOR swizzle: chunk kc at kc^(c&31)
    __shared__ float YL[64*128];
    int tid = threadIdx.x;
    int n_act = *nactp;
    int cb = blockIdx.x * 64;

    for (int i = tid; i < 64*32; i += 512) {
        int c = i >> 5, kc = i & 31;
        float4 val = (cb + c < n_act) ? ((const float4*)x17g)[(size_t)(cb+c)*32 + kc]
                                      : make_float4(0.f,0.f,0.f,0.f);
        ((float4*)XL)[c*32 + (kc ^ (c & 31))] = val;
    }
    __syncthreads();

    int wv = __builtin_amdgcn_readfirstlane(tid >> 6);
    int c  = tid & 63;
    int ob = wv * 16;
    int cswz = c & 31;
    const float4* xrow = (const float4*)XL + c*32;
    const float4* W4p = (const float4*)W3;

#define DECLB(q) f32x2 ap_##q = {0.f, 0.f};
#define ACCB(q) { const f32x2* wp_ = (const f32x2*)(W4p + (ob+(q))*32 + kc); \
    ap_##q += xv01 * wp_[0]; ap_##q += xv23 * wp_[1]; }
#define ACTB(q) float a_##q; { float yy = (ap_##q.x + ap_##q.y) * fold[336+ob+(q)] + fold[464+ob+(q)]; a_##q = mishf(yy); }
    {
        REP16_0(DECLB)
        for (int kc = 0; kc < 32; kc++) {
            float4 xv = xrow[kc ^ cswz];
            f32x2 xv01 = {xv.x, xv.y}, xv23 = {xv.z, xv.w};
            REP16_0(ACCB)
        }
        REP16_0(ACTB)
        ((float4*)YL)[c*32 + ((wv*4 + 0) ^ cswz)] = make_float4(a_0,  a_1,  a_2,  a_3);
        ((float4*)YL)[c*32 + ((wv*4 + 1) ^ cswz)] = make_float4(a_4,  a_5,  a_6,  a_7);
        ((float4*)YL)[c*32 + ((wv*4 + 2) ^ cswz)] = make_float4(a_8,  a_9,  a_10, a_11);
        ((float4*)YL)[c*32 + ((wv*4 + 3) ^ cswz)] = make_float4(a_12, a_13, a_14, a_15);
    }
    __syncthreads();

    {
        bool active = (cb + c) < n_act;
        int cell = active ? act[cb + c] : 0;
        int hh = cell / BEVW;
        int ww = cell - hh * BEVW;
        float* op = out + (size_t)ob*NCELL + ww*BEVH + hh;
        const float4* yrow = (const float4*)YL + c*32;
        REP16_0(DECLB)
        for (int kc = 0; kc < 32; kc++) {
            float4 xv = yrow[kc ^ cswz];
            f32x2 xv01 = {xv.x, xv.y}, xv23 = {xv.z, xv.w};
            REP16_0(ACCB)
        }
        REP16_0(ACTB)
        if (active) {
#define STOR(q) op[(q)*NCELL] = a_##q;
            REP16_0(STOR)
#undef STOR
        }
    }
#undef DECLB
#undef ACCB
#undef ACTB
}

extern "C" void kernel_launch(void* const* d_in, const int* in_sizes, int n_in,
                              void* d_out, int out_size, void* d_ws, size_t ws_size,
                              hipStream_t stream) {
    const float* features = (const float*)d_in[0];
    const int*   coors    = (const int*)d_in[1];
    const int*   num_vox  = (const int*)d_in[2];
    const float* vfe1_W   = (const float*)d_in[3];
    const float* vfe1_bn  = (const float*)d_in[4];
    const float* vfe2_W   = (const float*)d_in[5];
    const float* vfe2_bn  = (const float*)d_in[6];
    const float* vfe3_W   = (const float*)d_in[7];
    const float* vfe3_bn  = (const float*)d_in[8];
    const float* vfe4_W   = (const float*)d_in[9];
    const float* vfe4_bn  = (const float*)d_in[10];
    const float* bfe1_W   = (const float*)d_in[11];
    const float* bfe1_bn  = (const float*)d_in[12];
    const float* bfe2_W   = (const float*)d_in[13];
    const float* bfe2_bn  = (const float*)d_in[14];
    const float* bfe3_W   = (const float*)d_in[15];
    const float* bfe3_bn  = (const float*)d_in[16];
    float* out = (float*)d_out;

    char* ws = (char*)d_ws;
    int*   nact      = (int*)ws;
    int*   cnt       = (int*)(ws + 256);
    int*   list      = (int*)(ws + 857600);
    float* voxelwise = (float*)(ws + 14571008);
    int*   act       = (int*)(ws + 24811008);
    float* x17g      = (float*)(ws + 24971008);
    float* fold      = (float*)(ws + 45451008);
    float* w4t       = (float*)(ws + 45455680);

    (void)hipMemsetAsync(ws, 0, 857600, stream);
    (void)hipMemsetAsync(d_out, 0, (size_t)out_size * sizeof(float), stream);

    setup_kernel<<<1, 256, 0, stream>>>(vfe1_bn, vfe2_bn, vfe3_bn, vfe4_bn,
                                        bfe1_bn, bfe2_bn, bfe3_bn, vfe4_W,
                                        fold, w4t);
    vfe_kernel<<<NVOX/8, 256, 0, stream>>>(features, coors, num_vox,
                                           vfe1_W, vfe2_W, vfe3_W, w4t, fold,
                                           voxelwise, cnt, list, nact, act);
    bfe_front<<<NVOX/4, 256, 0, stream>>>(nact, act, cnt, list, voxelwise,
                                          bfe1_W, bfe2_W, fold, x17g);
    bfe3_fused<<<(NVOX+63)/64, 512, 0, stream>>>(nact, act, bfe3_W, fold, x17g, out);
}

// Round 9
// 593.910 us; speedup vs baseline: 2.5623x; 1.1473x over previous
//
#include <hip/hip_runtime.h>

#define BEVW 432
#define BEVH 496
#define NCELL (BEVW*BEVH)      // 214272
#define NVOX  40000
#define EPSB  1e-5f

typedef float f32x2 __attribute__((ext_vector_type(2)));
typedef float f32x4 __attribute__((ext_vector_type(4)));
typedef unsigned int u32x4 __attribute__((ext_vector_type(4)));
typedef short bf16x8 __attribute__((ext_vector_type(8)));   // 8 bf16 (guide-verified operand type)

// ---- repeat macros (token-pasted literal indices) ----
#define REP8_0(M)  M(0) M(1) M(2) M(3) M(4) M(5) M(6) M(7)
#define REP8_8(M)  M(8) M(9) M(10) M(11) M(12) M(13) M(14) M(15)
#define REP8_16(M) M(16) M(17) M(18) M(19) M(20) M(21) M(22) M(23)
#define REP8_24(M) M(24) M(25) M(26) M(27) M(28) M(29) M(30) M(31)
#define REP16_0(M)  REP8_0(M)  REP8_8(M)
#define REP32_0(M) REP16_0(M) REP8_16(M) REP8_24(M)

// ---------------- workspace layout (bytes) ----------------
// 0        : int nact (zeroed) | 256: int cnt[NCELL] (zeroed)
// 857600   : int list[NCELL*16]
// 14571008 : float voxelwise[NVOX*64]
// 24811008 : int act[NVOX]
// 24971008 : float x17g[NVOX*128]
// 45451008 : float fold[1168]
// 45455680 : ushort w4fh[4096]   (W4^T bf16-hi B-fragments)
// 45463872 : ushort w4fl[4096]   (W4^T bf16-lo B-fragments)

__device__ __forceinline__ float mishf(float y) {
    float e = __expf(fminf(y, 40.f));
    float n = e * (e + 2.f);
    return y * n * __builtin_amdgcn_rcpf(n + 2.f);
}

template <int CTRL>
__device__ __forceinline__ float dppmaxf(float a) {
    int p = __builtin_amdgcn_update_dpp(0, __float_as_int(a), CTRL, 0xF, 0xF, true);
    return fmaxf(a, __int_as_float(p));
}
#define WMAX32(a) { \
    a = dppmaxf<0xB1>(a); \
    a = dppmaxf<0x4E>(a); \
    a = dppmaxf<0x141>(a); \
    a = dppmaxf<0x140>(a); \
    a = fmaxf(a, __int_as_float(__builtin_amdgcn_ds_swizzle(__float_as_int(a), 0x401F))); }

__device__ __forceinline__ bf16x8 mkbf8(uint a, uint b, uint c, uint d) {
    u32x4 t = {a, b, c, d};
    return __builtin_bit_cast(bf16x8, t);
}

// split fp32 -> (hi bf16 | lo bf16 << 16), RNE both
__device__ __forceinline__ uint splitbf(float x) {
    uint ux = __float_as_uint(x);
    uint rh = (ux + 0x7FFFu + ((ux >> 16) & 1u)) & 0xFFFF0000u;
    float lof = x - __uint_as_float(rh);
    uint ul = __float_as_uint(lof);
    uint rl = (ul + 0x7FFFu + ((ul >> 16) & 1u)) >> 16;
    return (rh >> 16) | (rl << 16);
}

// fold layout: vfe1 s@0 t@8 | vfe2 s@16 t@48 | vfe3 s@80 t@144 | vfe4 s@208 t@272
// bfe3 s@336 t@464 | bfe1 s@592 t@848 | bfe2 s@1104 t@1136
__global__ __launch_bounds__(256) void setup_kernel(
    const float* __restrict__ vbn1, const float* __restrict__ vbn2,
    const float* __restrict__ vbn3, const float* __restrict__ vbn4,
    const float* __restrict__ bbn1, const float* __restrict__ bbn2,
    const float* __restrict__ bbn3, const float* __restrict__ W4,
    float* __restrict__ fold, ushort* __restrict__ w4fh, ushort* __restrict__ w4fl)
{
    int tid = threadIdx.x;
    if (tid < 8)  { float s = vbn1[tid]/sqrtf(vbn1[24+tid]+EPSB);  fold[tid]      = s; fold[8+tid]   = vbn1[8+tid]  - vbn1[16+tid]*s; }
    if (tid < 32) { float s = vbn2[tid]/sqrtf(vbn2[96+tid]+EPSB);  fold[16+tid]   = s; fold[48+tid]  = vbn2[32+tid] - vbn2[64+tid]*s; }
    if (tid < 64) { float s = vbn3[tid]/sqrtf(vbn3[192+tid]+EPSB); fold[80+tid]   = s; fold[144+tid] = vbn3[64+tid] - vbn3[128+tid]*s; }
    if (tid < 64) { float s = vbn4[tid]/sqrtf(vbn4[192+tid]+EPSB); fold[208+tid]  = s; fold[272+tid] = vbn4[64+tid] - vbn4[128+tid]*s; }
    if (tid < 128){ float s = bbn3[tid]/sqrtf(bbn3[384+tid]+EPSB); fold[336+tid]  = s; fold[464+tid] = bbn3[128+tid]- bbn3[256+tid]*s; }
    { int g = tid >> 4, q = tid & 15;
      const float* b = bbn1 + g*64;
      float s = b[q]/sqrtf(b[48+q]+EPSB);
      fold[592+tid] = s; fold[848+tid] = b[16+q] - b[32+q]*s; }
    if (tid < 32) { int g = tid >> 1, c = tid & 1;
      const float* b = bbn2 + g*8;
      float s = b[c]/sqrtf(b[6+c]+EPSB);
      fold[1104+tid] = s; fold[1136+tid] = b[2+c] - b[4+c]*s; }

    // W4^T B-fragments (B[k=o][n=q] = W4[q][o]), split bf16 hi/lo.
    // frag idx = ((kc*4 + nt)*64 + lane)*8 + j ; n = (lane&15)+16nt ; k = kc*32 + (lane>>4)*8 + j
    for (int i = tid; i < 4096; i += 256) {
        int j = i & 7, ln = (i >> 3) & 63, nt = (i >> 9) & 3, kc = i >> 11;
        int n = (ln & 15) + nt*16;
        int k = kc*32 + (ln >> 4)*8 + j;
        float val = W4[n*64 + k];
        uint ux = __float_as_uint(val);
        uint rh = (ux + 0x7FFFu + ((ux >> 16) & 1u)) & 0xFFFF0000u;
        float lof = val - __uint_as_float(rh);
        uint ul = __float_as_uint(lof);
        uint rl = (ul + 0x7FFFu + ((ul >> 16) & 1u)) >> 16;
        w4fh[i] = (ushort)(rh >> 16);
        w4fl[i] = (ushort)rl;
    }
}

// pair list: (pair index, scalar a, scalar b)
#define PAIRS(M) M(0,0,1) M(1,2,3) M(2,4,5) M(3,6,7) M(4,8,9) M(5,10,11) \
  M(6,12,13) M(7,14,15) M(8,16,17) M(9,18,19) M(10,20,21) M(11,22,23) \
  M(12,24,25) M(13,26,27) M(14,28,29) M(15,30,31)

#define MF3(D, AH, AL, BH, BL) \
    D = __builtin_amdgcn_mfma_f32_16x16x32_bf16(AL, BH, D, 0, 0, 0); \
    D = __builtin_amdgcn_mfma_f32_16x16x32_bf16(AH, BL, D, 0, 0, 0); \
    D = __builtin_amdgcn_mfma_f32_16x16x32_bf16(AH, BH, D, 0, 0, 0);

// ---------------- VFE: 8 voxels / 256-thr block; fe4 on matrix cores ----------------
// wave = 2 voxels (64 points). fe3 (VALU) streams x3 hi|lo u32 into stride-33 LDS;
// fe4 = 96 mfma_f32_16x16x32_bf16 (split-bf16 3-product). Residual+pool in C-layout.
__global__ __launch_bounds__(256, 2) void vfe_kernel(
    const float* __restrict__ feat, const int* __restrict__ coors,
    const int* __restrict__ nvx,
    const float* __restrict__ W1, const float* __restrict__ W2,
    const float* __restrict__ W3,
    const ushort* __restrict__ w4fh, const ushort* __restrict__ w4fl,
    const float* __restrict__ fold,
    float* __restrict__ voxelwise, int* __restrict__ cnt,
    int* __restrict__ list, int* __restrict__ nact, int* __restrict__ act)
{
    __shared__ char ldsbuf[4*8704];   // per wave: 64x33 u32 (x3/x2resid) + 64 f32 aggL
    int tid = threadIdx.x;
    int lane = tid & 63;
    int wv = tid >> 6;
    int quad = lane >> 4;
    int v = blockIdx.x * 8 + (tid >> 5);      // per-lane voxel
    int vA = blockIdx.x * 8 + 2*wv;           // wave's first voxel
    int t = tid & 31;
    uint*  x3w  = (uint*)(ldsbuf + wv*8704);
    float* xw   = (float*)x3w;
    float* aggL = (float*)(ldsbuf + wv*8704 + 8448);

    const float* fp = feat + (v*32 + t)*8;
    float4 fa = *(const float4*)fp;
    float4 fb = *(const float4*)(fp+4);
    int numv = nvx[v];
    float maskf = (t < numv) ? 1.f : 0.f;

    // ---- fe1 (8->8) + pool ----
#define D1(o) float x1_##o; float m1_##o;
    REP8_0(D1)
#undef D1
#define FE1(o) { const float* w = W1 + (o)*8; \
    float ya = fa.x*w[0] + fa.y*w[1]; float yb = fa.z*w[2] + fa.w*w[3]; \
    float yc = fb.x*w[4] + fb.y*w[5]; float yd = fb.z*w[6] + fb.w*w[7]; \
    float yy = ((ya+yb)+(yc+yd)) * fold[(o)] + fold[8+(o)]; \
    x1_##o = mishf(yy); }
    REP8_0(FE1)
#undef FE1
#define P1(o) { float a = x1_##o; WMAX32(a); m1_##o = a; }
    REP8_0(P1)
#undef P1

    f32x2 x1p_0 = {x1_0,x1_1}, x1p_1 = {x1_2,x1_3}, x1p_2 = {x1_4,x1_5}, x1p_3 = {x1_6,x1_7};
    f32x2 m1p_0 = {m1_0,m1_1}, m1p_1 = {m1_2,m1_3}, m1p_2 = {m1_4,m1_5}, m1p_3 = {m1_6,m1_7};

    // ---- fe2 (16->32) + pool ----
#define D2(o) float x2_##o; float agg_##o;
    REP32_0(D2)
#undef D2
#define FE2(o) { const f32x2* wp = (const f32x2*)(W2 + (o)*16); \
    f32x2 sa = x1p_0*wp[0]; sa += x1p_1*wp[1]; \
    f32x2 sb = x1p_2*wp[2]; sb += x1p_3*wp[3]; \
    f32x2 sc = m1p_0*wp[4]; sc += m1p_1*wp[5]; \
    f32x2 sd = m1p_2*wp[6]; sd += m1p_3*wp[7]; \
    sa += sb; sc += sd; sa += sc; \
    float yy = (sa.x + sa.y) * fold[16+(o)] + fold[48+(o)]; \
    x2_##o = mishf(yy); }
    REP32_0(FE2)
#undef FE2
#define P2(o) { float a = x2_##o; WMAX32(a); agg_##o = a; }
    REP32_0(P2)
#undef P2

#define PX(i,a,b) f32x2 x2p_##i = {x2_##a, x2_##b}; f32x2 aggp_##i = {agg_##a, agg_##b};
    PAIRS(PX)
#undef PX

    // ---- yagg: fe3 contribution of voxel-uniform aggregate half ----
    const f32x2* wap = (const f32x2*)(W3 + t*64 + 32);
    const f32x2* wbp = (const f32x2*)(W3 + (t+32)*64 + 32);
    f32x2 yp1 = {0.f,0.f}, yp2 = {0.f,0.f};
#define YG(i) yp1 += aggp_##i * wap[i]; yp2 += aggp_##i * wbp[i];
    REP16_0(YG)
#undef YG
    float yagg1 = yp1.x + yp1.y, yagg2 = yp2.x + yp2.y;

    f32x2 maskp = {maskf, maskf};
#define MSK(i) x2p_##i *= maskp; aggp_##i *= maskp;
    REP16_0(MSK)
#undef MSK

    // aggL: exact fp32 unmasked agg (lane t==0 is always valid -> its masked copy == unmasked)
    if (t == 0) {
        float* ag = aggL + (lane >> 5)*32;
#define AGW(i) ag[2*(i)] = aggp_##i.x; ag[2*(i)+1] = aggp_##i.y;
        REP16_0(AGW)
#undef AGW
    }

    int nA = __shfl(numv, 0);
    int nB = __shfl(numv, 32);

    // ---- fe4 accumulators (MFMA C tiles, 16 x f32x4) ----
#define DD(i) f32x4 d_##i = {0.f,0.f,0.f,0.f};
    REP16_0(DD)
#undef DD

    // ---- fe3 (VALU, streamed by 32-o chunk) + fe4 (MFMA) ----
    for (int kc = 0; kc < 2; kc++) {
        float ysrc = kc ? yagg2 : yagg1;
        for (int o = 0; o < 32; o++) {
            int og = kc*32 + o;
            const f32x2* wp = (const f32x2*)(W3 + og*64);
            f32x2 s0 = x2p_0*wp[0];  s0 += x2p_1*wp[1];  s0 += x2p_2*wp[2];  s0 += x2p_3*wp[3];
            f32x2 s1 = x2p_4*wp[4];  s1 += x2p_5*wp[5];  s1 += x2p_6*wp[6];  s1 += x2p_7*wp[7];
            f32x2 s2 = x2p_8*wp[8];  s2 += x2p_9*wp[9];  s2 += x2p_10*wp[10]; s2 += x2p_11*wp[11];
            f32x2 s3 = x2p_12*wp[12]; s3 += x2p_13*wp[13]; s3 += x2p_14*wp[14]; s3 += x2p_15*wp[15];
            s0 += s1; s2 += s3; s0 += s2;
            float ya = __shfl(ysrc, o, 32);
            float yy = (s0.x + s0.y) + maskf * ya;
            yy = yy * fold[80+og] + fold[144+og];
            x3w[lane*33 + o] = splitbf(mishf(yy));
        }
        __syncthreads();

        // B fragments for this kc (L1-hot global)
        const uint4* bh = (const uint4*)w4fh + (kc*4)*64 + lane;
        const uint4* bl = (const uint4*)w4fl + (kc*4)*64 + lane;
        uint4 h0 = bh[0], h1 = bh[64], h2 = bh[128], h3 = bh[192];
        uint4 l0 = bl[0], l1 = bl[64], l2 = bl[128], l3 = bl[192];
        bf16x8 Bh0 = mkbf8(h0.x,h0.y,h0.z,h0.w), Bh1 = mkbf8(h1.x,h1.y,h1.z,h1.w);
        bf16x8 Bh2 = mkbf8(h2.x,h2.y,h2.z,h2.w), Bh3 = mkbf8(h3.x,h3.y,h3.z,h3.w);
        bf16x8 Bl0 = mkbf8(l0.x,l0.y,l0.z,l0.w), Bl1 = mkbf8(l1.x,l1.y,l1.z,l1.w);
        bf16x8 Bl2 = mkbf8(l2.x,l2.y,l2.z,l2.w), Bl3 = mkbf8(l3.x,l3.y,l3.z,l3.w);

#define DOMT(mt, D0, D1, D2, D3) { \
    int aoff = ((lane & 15) + 16*(mt))*33 + quad*8; \
    uint u0 = x3w[aoff+0], u1 = x3w[aoff+1], u2 = x3w[aoff+2], u3 = x3w[aoff+3]; \
    uint u4 = x3w[aoff+4], u5 = x3w[aoff+5], u6 = x3w[aoff+6], u7 = x3w[aoff+7]; \
    bf16x8 Ah = mkbf8(__builtin_amdgcn_perm(u1,u0,0x05040100), __builtin_amdgcn_perm(u3,u2,0x05040100), \
                      __builtin_amdgcn_perm(u5,u4,0x05040100), __builtin_amdgcn_perm(u7,u6,0x05040100)); \
    bf16x8 Al = mkbf8(__builtin_amdgcn_perm(u1,u0,0x07060302), __builtin_amdgcn_perm(u3,u2,0x07060302), \
                      __builtin_amdgcn_perm(u5,u4,0x07060302), __builtin_amdgcn_perm(u7,u6,0x07060302)); \
    MF3(d_##D0, Ah, Al, Bh0, Bl0) MF3(d_##D1, Ah, Al, Bh1, Bl1) \
    MF3(d_##D2, Ah, Al, Bh2, Bl2) MF3(d_##D3, Ah, Al, Bh3, Bl3) }

        DOMT(0, 0, 1, 2, 3)
        DOMT(1, 4, 5, 6, 7)
        DOMT(2, 8, 9, 10, 11)
        DOMT(3, 12, 13, 14, 15)
#undef DOMT
        __syncthreads();   // before next chunk overwrites x3w
    }

    // ---- stage exact fp32 masked pointwise x2 for the residual (reuse x3w) ----
#define XWR(i) xw[lane*33 + 2*(i)] = x2p_##i.x; xw[lane*33 + 2*(i)+1] = x2p_##i.y;
    REP16_0(XWR)
#undef XWR
    __syncthreads();

    // ---- bn4 + mish + residual + pool, in C layout (col=lane&15+16nt, row=quad*4+r+16mt) ----
    int c0 = lane & 15;
    float s0f = fold[208+c0],    t0f = fold[272+c0];
    float s1f = fold[208+16+c0], t1f = fold[272+16+c0];
    float s2f = fold[208+32+c0], t2f = fold[272+32+c0];
    float s3f = fold[208+48+c0], t3f = fold[272+48+c0];
    float rA2 = aggL[c0],      rA3 = aggL[16+c0];
    float rB2 = aggL[32+c0],   rB3 = aggL[48+c0];
    float pA0=-3.4e38f, pA1=-3.4e38f, pA2=-3.4e38f, pA3=-3.4e38f;
    float pB0=-3.4e38f, pB1=-3.4e38f, pB2=-3.4e38f, pB3=-3.4e38f;

#define FTP(D, mt, nt, SS, TT, PV) { \
    int nv = ((mt) >> 1) ? nB : nA; \
    int rf = quad*4 + 16*(mt); \
    int rt = quad*4 + 16*((mt)&1); \
    int cb = c0 + 16*(nt); \
    float m0=(rt+0<nv)?1.f:0.f, m1=(rt+1<nv)?1.f:0.f, m2=(rt+2<nv)?1.f:0.f, m3=(rt+3<nv)?1.f:0.f; \
    float y0 = mishf(D.x*SS + TT)*m0 + xw[(rf+0)*33 + cb]; \
    float y1 = mishf(D.y*SS + TT)*m1 + xw[(rf+1)*33 + cb]; \
    float y2 = mishf(D.z*SS + TT)*m2 + xw[(rf+2)*33 + cb]; \
    float y3 = mishf(D.w*SS + TT)*m3 + xw[(rf+3)*33 + cb]; \
    PV = fmaxf(PV, fmaxf(fmaxf(y0,y1), fmaxf(y2,y3))); }

#define FTA(D, mt, nt, SS, TT, AG, PV) { \
    int nv = ((mt) >> 1) ? nB : nA; \
    int rt = quad*4 + 16*((mt)&1); \
    float m0=(rt+0<nv)?1.f:0.f, m1=(rt+1<nv)?1.f:0.f, m2=(rt+2<nv)?1.f:0.f, m3=(rt+3<nv)?1.f:0.f; \
    float y0 = (mishf(D.x*SS + TT) + AG)*m0; \
    float y1 = (mishf(D.y*SS + TT) + AG)*m1; \
    float y2 = (mishf(D.z*SS + TT) + AG)*m2; \
    float y3 = (mishf(D.w*SS + TT) + AG)*m3; \
    PV = fmaxf(PV, fmaxf(fmaxf(y0,y1), fmaxf(y2,y3))); }

    FTP(d_0, 0, 0, s0f, t0f, pA0)  FTP(d_1, 0, 1, s1f, t1f, pA1)
    FTA(d_2, 0, 2, s2f, t2f, rA2, pA2)  FTA(d_3, 0, 3, s3f, t3f, rA3, pA3)
    FTP(d_4, 1, 0, s0f, t0f, pA0)  FTP(d_5, 1, 1, s1f, t1f, pA1)
    FTA(d_6, 1, 2, s2f, t2f, rA2, pA2)  FTA(d_7, 1, 3, s3f, t3f, rA3, pA3)
    FTP(d_8, 2, 0, s0f, t0f, pB0)  FTP(d_9, 2, 1, s1f, t1f, pB1)
    FTA(d_10, 2, 2, s2f, t2f, rB2, pB2)  FTA(d_11, 2, 3, s3f, t3f, rB3, pB3)
    FTP(d_12, 3, 0, s0f, t0f, pB0)  FTP(d_13, 3, 1, s1f, t1f, pB1)
    FTA(d_14, 3, 2, s2f, t2f, rB2, pB2)  FTA(d_15, 3, 3, s3f, t3f, rB3, pB3)
#undef FTP
#undef FTA

#define RED(p) p = fmaxf(p, __shfl_xor(p, 16)); p = fmaxf(p, __shfl_xor(p, 32));
    RED(pA0) RED(pA1) RED(pA2) RED(pA3) RED(pB0) RED(pB1) RED(pB2) RED(pB3)
#undef RED

    if (quad == 0) {
        float* vwA = voxelwise + vA*64;
        vwA[c0] = pA0; vwA[c0+16] = pA1; vwA[c0+32] = pA2; vwA[c0+48] = pA3;
        float* vwB = voxelwise + (vA+1)*64;
        vwB[c0] = pB0; vwB[c0+16] = pB1; vwB[c0+32] = pB2; vwB[c0+48] = pB3;
    }

    if (t == 0) {
        int cell = coors[v*2] * BEVW + coors[v*2+1];
        int pos = atomicAdd(&cnt[cell], 1);
        if (pos < 16) list[cell*16 + pos] = v;
        if (pos == 0) { int k = atomicAdd(nact, 1); act[k] = cell; }
    }
}

// ---------------- BFE front: 1 wave = 1 cell; weights direct from L1 ----------------
__global__ __launch_bounds__(256) void bfe_front(
    const int* __restrict__ nact, const int* __restrict__ act,
    const int* __restrict__ cnt, const int* __restrict__ list,
    const float* __restrict__ voxelwise,
    const float* __restrict__ W1g, const float* __restrict__ W2g,
    const float* __restrict__ fold, float* __restrict__ x17g)
{
    int n_act = *nact;
    int aidx = blockIdx.x * 4 + (threadIdx.x >> 6);
    if (aidx >= n_act) return;

    int lane = threadIdx.x & 63;
    int g = lane >> 2, ii = lane & 3;
    int cell = act[aidx];
    int numv = min(cnt[cell], 16);

    int myidx = (lane < numv) ? list[cell*16 + lane] : (0x40000000 + lane);
    int rank = 0;
    for (int j = 0; j < numv; j++) { int vj = __shfl(myidx, j); rank += (vj < myidx) ? 1 : 0; }
    if (lane >= numv) rank = lane;
    int sorted = __builtin_amdgcn_ds_permute(rank << 2, myidx);

#define YD(q) float y_##q = 0.f;
    REP16_0(YD)
#undef YD
    for (int p = 0; p < numv; p++) {
        int sv = __shfl(sorted, p);
        float val = voxelwise[sv*64 + lane];
        const float* w = W1g + g*256 + p;
#define BF1(q) y_##q += val * w[(q)*16];
        REP16_0(BF1)
#undef BF1
    }
#define BN1(q) { float yy = y_##q * fold[592 + g*16 + (q)] + fold[848 + g*16 + (q)]; \
    yy = mishf(yy); y_##q = ((q) < numv) ? yy : 0.f; }
    REP16_0(BN1)
#undef BN1

    float z0 = 0.f, z1 = 0.f;
#define BF2(p) z0 += y_##p * W2g[g*32 + (p)]; z1 += y_##p * W2g[g*32 + 16 + (p)];
    REP16_0(BF2)
#undef BF2
    z0 = mishf(z0 * fold[1104 + g*2 + 0] + fold[1136 + g*2 + 0]);
    z1 = mishf(z1 * fold[1104 + g*2 + 1] + fold[1136 + g*2 + 1]);

    int k0 = ii*32 + g*2;
    *(float2*)(x17g + aidx*128 + k0) = make_float2(z0, z1);
}

// ---------------- bfe3 fused (x18 and x19): GEMM-shaped, XL reused (32 KB) ----------------
__global__ __launch_bounds__(512, 4) void bfe3_fused(
    const int* __restrict__ nactp, const int* __restrict__ act,
    const float* __restrict__ W3, const float* __restrict__ fold,
    const float* __restrict__ x17g, float* __restrict__ out)
{
    __shared__ float XL[64*128];   // float4-chunk XOR swizzle: chunk kc at kc^(c&31)
    int tid = threadIdx.x;
    int n_act = *nactp;
    int cb = blockIdx.x * 64;

    for (int i = tid; i < 64*32; i += 512) {
        int c = i >> 5, kc = i & 31;
        float4 val = (cb + c < n_act) ? ((const float4*)x17g)[(size_t)(cb+c)*32 + kc]
                                      : make_float4(0.f,0.f,0.f,0.f);
        ((float4*)XL)[c*32 + (kc ^ (c & 31))] = val;
    }
    __syncthreads();

    int wv = __builtin_amdgcn_readfirstlane(tid >> 6);
    int c  = tid & 63;
    int ob = wv * 16;
    int cswz = c & 31;
    const float4* xrow = (const float4*)XL + c*32;
    const float4* W4p = (const float4*)W3;

#define DECLB(q) f32x2 ap_##q = {0.f, 0.f};
#define ACCB(q) { const f32x2* wp_ = (const f32x2*)(W4p + (ob+(q))*32 + kc); \
    ap_##q += xv01 * wp_[0]; ap_##q += xv23 * wp_[1]; }
#define ACTB(q) float a_##q; { float yy = (ap_##q.x + ap_##q.y) * fold[336+ob+(q)] + fold[464+ob+(q)]; a_##q = mishf(yy); }
    {
        REP16_0(DECLB)
        for (int kc = 0; kc < 32; kc++) {
            float4 xv = xrow[kc ^ cswz];
            f32x2 xv01 = {xv.x, xv.y}, xv23 = {xv.z, xv.w};
            REP16_0(ACCB)
        }
        REP16_0(ACTB)
        __syncthreads();   // everyone done READING XL
        ((float4*)XL)[c*32 + ((wv*4 + 0) ^ cswz)] = make_float4(a_0,  a_1,  a_2,  a_3);
        ((float4*)XL)[c*32 + ((wv*4 + 1) ^ cswz)] = make_float4(a_4,  a_5,  a_6,  a_7);
        ((float4*)XL)[c*32 + ((wv*4 + 2) ^ cswz)] = make_float4(a_8,  a_9,  a_10, a_11);
        ((float4*)XL)[c*32 + ((wv*4 + 3) ^ cswz)] = make_float4(a_12, a_13, a_14, a_15);
    }
    __syncthreads();

    {
        bool active = (cb + c) < n_act;
        int cell = active ? act[cb + c] : 0;
        int hh = cell / BEVW;
        int ww = cell - hh * BEVW;
        float* op = out + (size_t)ob*NCELL + ww*BEVH + hh;
        const float4* yrow = (const float4*)XL + c*32;
        REP16_0(DECLB)
        for (int kc = 0; kc < 32; kc++) {
            float4 xv = yrow[kc ^ cswz];
            f32x2 xv01 = {xv.x, xv.y}, xv23 = {xv.z, xv.w};
            REP16_0(ACCB)
        }
        REP16_0(ACTB)
        if (active) {
#define STOR(q) op[(q)*NCELL] = a_##q;
            REP16_0(STOR)
#undef STOR
        }
    }
#undef DECLB
#undef ACCB
#undef ACTB
}

extern "C" void kernel_launch(void* const* d_in, const int* in_sizes, int n_in,
                              void* d_out, int out_size, void* d_ws, size_t ws_size,
                              hipStream_t stream) {
    const float* features = (const float*)d_in[0];
    const int*   coors    = (const int*)d_in[1];
    const int*   num_vox  = (const int*)d_in[2];
    const float* vfe1_W   = (const float*)d_in[3];
    const float* vfe1_bn  = (const float*)d_in[4];
    const float* vfe2_W   = (const float*)d_in[5];
    const float* vfe2_bn  = (const float*)d_in[6];
    const float* vfe3_W   = (const float*)d_in[7];
    const float* vfe3_bn  = (const float*)d_in[8];
    const float* vfe4_W   = (const float*)d_in[9];
    const float* vfe4_bn  = (const float*)d_in[10];
    const float* bfe1_W   = (const float*)d_in[11];
    const float* bfe1_bn  = (const float*)d_in[12];
    const float* bfe2_W   = (const float*)d_in[13];
    const float* bfe2_bn  = (const float*)d_in[14];
    const float* bfe3_W   = (const float*)d_in[15];
    const float* bfe3_bn  = (const float*)d_in[16];
    float* out = (float*)d_out;

    char* ws = (char*)d_ws;
    int*    nact      = (int*)ws;
    int*    cnt       = (int*)(ws + 256);
    int*    list      = (int*)(ws + 857600);
    float*  voxelwise = (float*)(ws + 14571008);
    int*    act       = (int*)(ws + 24811008);
    float*  x17g      = (float*)(ws + 24971008);
    float*  fold      = (float*)(ws + 45451008);
    ushort* w4fh      = (ushort*)(ws + 45455680);
    ushort* w4fl      = (ushort*)(ws + 45463872);

    (void)hipMemsetAsync(ws, 0, 857600, stream);
    (void)hipMemsetAsync(d_out, 0, (size_t)out_size * sizeof(float), stream);

    setup_kernel<<<1, 256, 0, stream>>>(vfe1_bn, vfe2_bn, vfe3_bn, vfe4_bn,
                                        bfe1_bn, bfe2_bn, bfe3_bn, vfe4_W,
                                        fold, w4fh, w4fl);
    vfe_kernel<<<NVOX/8, 256, 0, stream>>>(features, coors, num_vox,
                                           vfe1_W, vfe2_W, vfe3_W, w4fh, w4fl, fold,
                                           voxelwise, cnt, list, nact, act);
    bfe_front<<<NVOX/4, 256, 0, stream>>>(nact, act, cnt, list, voxelwise,
                                          bfe1_W, bfe2_W, fold, x17g);
    bfe3_fused<<<(NVOX+63)/64, 512, 0, stream>>>(nact, act, bfe3_W, fold, x17g, out);
}